// Round 2
// baseline (1253.886 us; speedup 1.0000x reference)
//
#include <hip/hip_runtime.h>
#include <math.h>

typedef short s16;
typedef __attribute__((ext_vector_type(8))) short short8;
typedef __attribute__((ext_vector_type(4))) float f32x4;

__device__ __forceinline__ float bf2f_lo(unsigned u){ return __builtin_bit_cast(float, u << 16); }
__device__ __forceinline__ float bf2f_hi(unsigned u){ return __builtin_bit_cast(float, u & 0xffff0000u); }
__device__ __forceinline__ float bf2f(unsigned short h){ return __builtin_bit_cast(float, (unsigned)h << 16); }
__device__ __forceinline__ s16 f2bf(float f){
  unsigned u = __builtin_bit_cast(unsigned, f);
  u += 0x7fffu + ((u >> 16) & 1u);
  return (s16)(u >> 16);
}
__device__ __forceinline__ void unpack8(int4 v, float* f){
  unsigned a=(unsigned)v.x, b=(unsigned)v.y, c=(unsigned)v.z, d=(unsigned)v.w;
  f[0]=bf2f_lo(a); f[1]=bf2f_hi(a); f[2]=bf2f_lo(b); f[3]=bf2f_hi(b);
  f[4]=bf2f_lo(c); f[5]=bf2f_hi(c); f[6]=bf2f_lo(d); f[7]=bf2f_hi(d);
}

// ---------------- LayerNorm (fp32 in) -> bf16 out, D=1024, 1 block/row ------
__global__ __launch_bounds__(256) void ln_bf16(const float* __restrict__ x,
                                               const float* __restrict__ w,
                                               const float* __restrict__ b,
                                               s16* __restrict__ out){
  int row = blockIdx.x; int t = threadIdx.x;
  const float* xr = x + (size_t)row * 1024;
  float4 v = *(const float4*)(xr + t*4);
  float s = v.x + v.y + v.z + v.w;
  float ss = v.x*v.x + v.y*v.y + v.z*v.z + v.w*v.w;
  for (int o = 32; o > 0; o >>= 1){ s += __shfl_down(s, o, 64); ss += __shfl_down(ss, o, 64); }
  __shared__ float red[8];
  int wid = t >> 6, lane = t & 63;
  if (lane == 0){ red[wid] = s; red[4+wid] = ss; }
  __syncthreads();
  if (t == 0){
    float S = red[0]+red[1]+red[2]+red[3];
    float SS = red[4]+red[5]+red[6]+red[7];
    red[0] = S * (1.f/1024.f);
    red[1] = SS * (1.f/1024.f);
  }
  __syncthreads();
  float mu = red[0];
  float var = red[1] - mu*mu;
  float rstd = rsqrtf(var + 1e-6f);
  float vv[4] = {v.x, v.y, v.z, v.w};
  short4 o4;
  s16 tmp[4];
  #pragma unroll
  for (int i = 0; i < 4; ++i){
    int c = t*4 + i;
    float val = (vv[i] - mu) * rstd * w[c] + b[c];
    tmp[i] = f2bf(val);
  }
  o4.x = tmp[0]; o4.y = tmp[1]; o4.z = tmp[2]; o4.w = tmp[3];
  *(short4*)(out + (size_t)row*1024 + t*4) = o4;
}

// ---------------- transpose-convert fp32 W[K,N] -> bf16 Wt[N,K], with scale --
__global__ __launch_bounds__(256) void conv_t(const float* __restrict__ W,
                                              s16* __restrict__ Wt,
                                              int K, int N, float scale){
  __shared__ float tile[32][33];
  int n0 = blockIdx.x * 32, k0 = blockIdx.y * 32;
  int tx = threadIdx.x & 31, ty = threadIdx.x >> 5;   // ty 0..7
  #pragma unroll
  for (int i = 0; i < 4; ++i){
    int r = ty + i*8;
    tile[r][tx] = W[(size_t)(k0 + r)*N + n0 + tx];
  }
  __syncthreads();
  #pragma unroll
  for (int i = 0; i < 4; ++i){
    int r = ty + i*8;
    Wt[(size_t)(n0 + r)*K + k0 + tx] = f2bf(tile[tx][r] * scale);
  }
}

// ---------------- bf16 MFMA GEMM:  C[M,N] = A[M,K] @ Bt[N,:]^T  --------------
// Bt row stride = ldb (>= K). flags: bit0 = gelu, bit1 = out bf16
__global__ __launch_bounds__(256,2) void gemm_nt(const s16* __restrict__ A,
                                                 const s16* __restrict__ Bt,
                                                 int M, int N, int K, int ldb,
                                                 float* __restrict__ Cf,
                                                 s16* __restrict__ Cb,
                                                 const float* __restrict__ bias,
                                                 const float* __restrict__ resid,
                                                 int flags){
  __shared__ s16 As[128*40];
  __shared__ s16 Bs[128*40];
  int t = threadIdx.x;
  int m0 = blockIdx.y * 128, n0 = blockIdx.x * 128;
  int w = t >> 6, lane = t & 63;
  int wm = (w >> 1) * 64, wn = (w & 1) * 64;
  int lrow = lane & 15, lq = lane >> 4;
  f32x4 acc[4][4];
  #pragma unroll
  for (int i = 0; i < 4; ++i)
    #pragma unroll
    for (int j = 0; j < 4; ++j) acc[i][j] = (f32x4){0.f,0.f,0.f,0.f};

  const s16* Aptr = A + (size_t)m0 * K;
  const s16* Bptr = Bt + (size_t)n0 * ldb;
  int r0 = t >> 2;            // 0..63
  int kq8 = (t & 3) * 8;      // 0,8,16,24

  for (int k0 = 0; k0 < K; k0 += 32){
    __syncthreads();
    int4 a0 = *(const int4*)(Aptr + (size_t)r0 * K + k0 + kq8);
    int4 a1 = *(const int4*)(Aptr + (size_t)(r0+64) * K + k0 + kq8);
    int4 b0 = *(const int4*)(Bptr + (size_t)r0 * ldb + k0 + kq8);
    int4 b1 = *(const int4*)(Bptr + (size_t)(r0+64) * ldb + k0 + kq8);
    *(int4*)&As[r0*40 + kq8]      = a0;
    *(int4*)&As[(r0+64)*40 + kq8] = a1;
    *(int4*)&Bs[r0*40 + kq8]      = b0;
    *(int4*)&Bs[(r0+64)*40 + kq8] = b1;
    __syncthreads();
    short8 af[4], bfr[4];
    #pragma unroll
    for (int mi = 0; mi < 4; ++mi)
      af[mi] = *(short8*)&As[(wm + mi*16 + lrow)*40 + lq*8];
    #pragma unroll
    for (int ni = 0; ni < 4; ++ni)
      bfr[ni] = *(short8*)&Bs[(wn + ni*16 + lrow)*40 + lq*8];
    #pragma unroll
    for (int mi = 0; mi < 4; ++mi)
      #pragma unroll
      for (int ni = 0; ni < 4; ++ni)
        acc[mi][ni] = __builtin_amdgcn_mfma_f32_16x16x32_bf16(af[mi], bfr[ni], acc[mi][ni], 0, 0, 0);
  }

  bool do_gelu = flags & 1;
  bool out_bf = flags & 2;
  #pragma unroll
  for (int mi = 0; mi < 4; ++mi){
    #pragma unroll
    for (int ni = 0; ni < 4; ++ni){
      int gcol = n0 + wn + ni*16 + lrow;
      float bcol = bias ? bias[gcol] : 0.f;
      int grow_base = m0 + wm + mi*16 + lq*4;
      #pragma unroll
      for (int r = 0; r < 4; ++r){
        int grow = grow_base + r;
        float val = acc[mi][ni][r] + bcol;
        if (do_gelu) val = 0.5f * val * (1.f + erff(val * 0.70710678118654752f));
        if (resid) val += resid[(size_t)grow * N + gcol];
        if (out_bf) Cb[(size_t)grow * N + gcol] = f2bf(val);
        else        Cf[(size_t)grow * N + gcol] = val;
      }
    }
  }
}

// ---------------- retention pass 1: A = (q k^T) * decay-mask (bf16 out) ------
// grid 1024 = bh(16) x chunk(64); q,k bf16 [8192,1024] (q pre-scaled by DK^-0.5)
__global__ __launch_bounds__(256,2) void ret_scores(const s16* __restrict__ q,
                                                    const s16* __restrict__ k,
                                                    s16* __restrict__ Abuf){
  int bi = blockIdx.x;
  int bh = bi & 15, n = bi >> 4;
  int b = bh >> 3, h = bh & 7;
  int t = threadIdx.x;
  __shared__ float qs[64*130];
  __shared__ s16 ks[64*130];
  float log2b = log2f(1.f - exp2f(-5.f - (float)h));
  const s16* qbase = q + ((size_t)(b*4096 + n*64))*1024 + h*128;
  const s16* kbase = k + ((size_t)(b*4096 + n*64))*1024 + h*128;
  #pragma unroll
  for (int i = 0; i < 4; ++i){
    int e = i*2048 + t*8;
    int row = e >> 7, col = e & 127;
    int4 qv = *(const int4*)(qbase + (size_t)row*1024 + col);
    int4 kv = *(const int4*)(kbase + (size_t)row*1024 + col);
    float f[8]; unpack8(qv, f);
    #pragma unroll
    for (int j = 0; j < 8; ++j) qs[row*130 + col + j] = f[j];
    int* kd = (int*)&ks[row*130 + col];
    kd[0] = kv.x; kd[1] = kv.y; kd[2] = kv.z; kd[3] = kv.w;
  }
  __syncthreads();
  int s = t & 63, tw = t >> 6;
  s16* Atile = Abuf + ((size_t)(bh*64 + n))*4096;
  #pragma unroll
  for (int i = 0; i < 16; ++i){
    int tt = i*4 + tw;
    float a = 0.f;
    #pragma unroll 16
    for (int dk = 0; dk < 128; dk += 2){
      float2 q2 = *(const float2*)&qs[tt*130 + dk];
      unsigned kw = *(const unsigned*)&ks[s*130 + dk];
      a += q2.x * bf2f_lo(kw);
      a += q2.y * bf2f_hi(kw);
    }
    int d = tt - s;
    float val = (d >= 0) ? a * exp2f(log2b * (float)d) : 0.f;
    Atile[tt*64 + s] = f2bf(val);
  }
}

// ---------------- retention pass 2 (per batch): chunk-state scan -------------
// grid 128 = h(8) x dkb(4) x dvb(4); S[h][n][128][256] bf16 (state BEFORE chunk n)
__global__ __launch_bounds__(256) void ret_state(const s16* __restrict__ k,
                                                 const s16* __restrict__ v,
                                                 s16* __restrict__ S){
  int bi = blockIdx.x;
  int h = bi & 7, dkb = (bi >> 3) & 3, dvb = bi >> 5;
  int dk0 = dkb*32, dv0 = dvb*64;
  int t = threadIdx.x;
  int dkl = t >> 3, j8 = t & 7;
  float log2b = log2f(1.f - exp2f(-5.f - (float)h));
  float dc = exp2f(log2b * 64.f);
  __shared__ float ks[64*33];
  __shared__ float vs[64*68];
  float st[8] = {0.f,0.f,0.f,0.f,0.f,0.f,0.f,0.f};
  const s16* kbase = k + (size_t)h*128 + dk0;
  const s16* vbase = v + (size_t)h*256 + dv0;
  s16* Sbase = S + ((size_t)(h*64))*32768 + (size_t)dk0*256 + dv0;
  int srow_k = t >> 2, ck = (t & 3)*8;
  float dkdecay = exp2f(log2b * (float)(63 - srow_k));
  for (int n = 0; n < 64; ++n){
    s16* sp = Sbase + (size_t)n*32768 + (size_t)dkl*256 + j8*8;
    s16 sb[8];
    #pragma unroll
    for (int j = 0; j < 8; ++j) sb[j] = f2bf(st[j]);
    *(int4*)sp = *(int4*)sb;
    // stage k slice (64 x 32) with d_k decay
    {
      int4 kv = *(const int4*)(kbase + (size_t)(n*64 + srow_k)*1024 + ck);
      float f[8]; unpack8(kv, f);
      #pragma unroll
      for (int j = 0; j < 8; ++j) ks[srow_k*33 + ck + j] = f[j] * dkdecay;
    }
    // stage v slice (64 x 64)
    #pragma unroll
    for (int i = 0; i < 2; ++i){
      int e = i*2048 + t*8;
      int sv = e >> 6, c = e & 63;
      int4 vv = *(const int4*)(vbase + (size_t)(n*64 + sv)*2048 + c);
      float f[8]; unpack8(vv, f);
      #pragma unroll
      for (int j = 0; j < 8; ++j) vs[sv*68 + c + j] = f[j];
    }
    __syncthreads();
    #pragma unroll
    for (int j = 0; j < 8; ++j) st[j] *= dc;
    #pragma unroll 8
    for (int s = 0; s < 64; ++s){
      float kv = ks[s*33 + dkl];
      float4 v0 = *(const float4*)&vs[s*68 + j8*8];
      float4 v1 = *(const float4*)&vs[s*68 + j8*8 + 4];
      st[0] += kv*v0.x; st[1] += kv*v0.y; st[2] += kv*v0.z; st[3] += kv*v0.w;
      st[4] += kv*v1.x; st[5] += kv*v1.y; st[6] += kv*v1.z; st[7] += kv*v1.w;
    }
    __syncthreads();
  }
}

// ---------------- retention pass 3 (per batch): o = A@v + d_q * (q @ S) ------
// grid 2048 = h(8) x chunk(64) x jb(4); o bf16 [4096, 2048]
__global__ __launch_bounds__(256,2) void ret_out(const s16* __restrict__ q,
                                                 const s16* __restrict__ v,
                                                 const s16* __restrict__ Abuf,
                                                 const s16* __restrict__ S,
                                                 s16* __restrict__ o){
  int bi = blockIdx.x;
  int jb = bi & 3, n = (bi >> 2) & 63, h = bi >> 8;
  int dv0 = jb * 64;
  int t = threadIdx.x;
  int j = t & 63, tg = t >> 6;
  float log2b = log2f(1.f - exp2f(-5.f - (float)h));
  __shared__ float qs[64*132];   // d_q-prescaled, fp32
  __shared__ float As[64*68];
  __shared__ s16 vsb[64*68];

  const s16* qbase = q + ((size_t)(n*64))*1024 + h*128;
  const s16* vbase = v + ((size_t)(n*64))*2048 + h*256 + dv0;
  const s16* Atile = Abuf + ((size_t)(h*64 + n))*4096;

  #pragma unroll
  for (int i = 0; i < 4; ++i){
    int e = i*2048 + t*8;
    int row = e >> 7, col = e & 127;
    int4 qv = *(const int4*)(qbase + (size_t)row*1024 + col);
    float f[8]; unpack8(qv, f);
    float dq = exp2f(log2b * (float)(row + 1));
    #pragma unroll
    for (int jj = 0; jj < 8; ++jj) qs[row*132 + col + jj] = f[jj] * dq;
  }
  #pragma unroll
  for (int i = 0; i < 2; ++i){
    int e = i*2048 + t*8;
    int tt = e >> 6, s = e & 63;
    int4 a8 = *(const int4*)(Atile + e);
    float f[8]; unpack8(a8, f);
    #pragma unroll
    for (int jj = 0; jj < 8; ++jj) As[tt*68 + s + jj] = f[jj];
  }
  #pragma unroll
  for (int i = 0; i < 2; ++i){
    int e = i*2048 + t*8;
    int sv = e >> 6, c = e & 63;
    int4 vv = *(const int4*)(vbase + (size_t)sv*2048 + c);
    int* vd = (int*)&vsb[sv*68 + c];
    vd[0] = vv.x; vd[1] = vv.y; vd[2] = vv.z; vd[3] = vv.w;
  }
  __syncthreads();

  float acc[16];
  #pragma unroll
  for (int i = 0; i < 16; ++i) acc[i] = 0.f;

  // A @ v
  for (int s = 0; s < 64; s += 4){
    float vv[4];
    #pragma unroll
    for (int u = 0; u < 4; ++u) vv[u] = bf2f((unsigned short)vsb[(s+u)*68 + j]);
    #pragma unroll
    for (int tt = 0; tt < 16; ++tt){
      float4 a4 = *(const float4*)&As[(tg*16 + tt)*68 + s];
      acc[tt] += a4.x*vv[0] + a4.y*vv[1] + a4.z*vv[2] + a4.w*vv[3];
    }
  }
  // d_q*q @ S
  const s16* Sb = S + ((size_t)(h*64 + n))*32768 + dv0 + j;
  for (int dk = 0; dk < 128; dk += 4){
    float sv[4];
    #pragma unroll
    for (int u = 0; u < 4; ++u) sv[u] = bf2f((unsigned short)Sb[(size_t)(dk+u)*256]);
    #pragma unroll
    for (int tt = 0; tt < 16; ++tt){
      float4 q4 = *(const float4*)&qs[(tg*16 + tt)*132 + dk];
      acc[tt] += q4.x*sv[0] + q4.y*sv[1] + q4.z*sv[2] + q4.w*sv[3];
    }
  }
  s16* obase = o + ((size_t)(n*64))*2048 + h*256 + dv0 + j;
  #pragma unroll
  for (int tt = 0; tt < 16; ++tt){
    int row = tg*16 + tt;
    obase[(size_t)row*2048] = f2bf(acc[tt]);
  }
}

extern "C" void kernel_launch(void* const* d_in, const int* in_sizes, int n_in,
                              void* d_out, int out_size, void* d_ws, size_t ws_size,
                              hipStream_t stream) {
  (void)in_sizes; (void)n_in; (void)out_size; (void)ws_size;
  const float* x     = (const float*)d_in[0];
  const float* ln1_w = (const float*)d_in[1];
  const float* ln1_b = (const float*)d_in[2];
  const float* Wq    = (const float*)d_in[3];
  const float* Wk    = (const float*)d_in[4];
  const float* Wv    = (const float*)d_in[5];
  const float* Wo    = (const float*)d_in[6];
  const float* ln2_w = (const float*)d_in[7];
  const float* ln2_b = (const float*)d_in[8];
  const float* W1    = (const float*)d_in[9];
  const float* b1    = (const float*)d_in[10];
  const float* W2    = (const float*)d_in[11];
  const float* b2    = (const float*)d_in[12];
  float* out = (float*)d_out;
  char* ws = (char*)d_ws;

  // ---- static arena, peak 172 MB (lifetime-aliased) ----
  const size_t MB = 1ull << 20;
  s16* Wq_t = (s16*)(ws + 0*MB);     // [0,2)
  s16* Wk_t = (s16*)(ws + 2*MB);     // [2,4)
  s16* Wv_t = (s16*)(ws + 4*MB);     // [4,8)
  s16* Wo_t = (s16*)(ws + 8*MB);     // [8,12)
  s16* W1_t = (s16*)(ws + 12*MB);    // [12,20)
  s16* W2_t = (s16*)(ws + 20*MB);    // [20,28)
  s16* hbuf = (s16*)(ws + 28*MB);    // [28,44)  dead after QKV gemms
  s16* Abuf = (s16*)(ws + 28*MB);    // [28,36)  bf16 scores, alias dead hbuf
  s16* h2   = (s16*)(ws + 28*MB);    // [28,44)  alias dead Abuf (post-retention)
  s16* qb   = (s16*)(ws + 44*MB);    // [44,60)  dead after ret_out(b1)
  s16* kb   = (s16*)(ws + 60*MB);    // [60,76)  dead after ret_state(b1)
  s16* vb   = (s16*)(ws + 76*MB);    // [76,108) dead after ret_out(b1)
  float* x1 = (float*)(ws + 44*MB);  // [44,76)  alias dead qb+kb (post-retention)
  s16* fb   = (s16*)(ws + 76*MB);    // [76,108) alias dead vb (FFN half, 8192x2048)
  s16* Sbuf = (s16*)(ws + 108*MB);   // [108,140) bf16 per-batch state, reused b0/b1
  s16* ob   = (s16*)(ws + 140*MB);   // [140,172)

  // weight transpose-convert (DK^-0.5 folded into Wq)
  conv_t<<<dim3(32,32),  256, 0, stream>>>(Wq, Wq_t, 1024, 1024, 0.08838834764831845f);
  conv_t<<<dim3(32,32),  256, 0, stream>>>(Wk, Wk_t, 1024, 1024, 1.f);
  conv_t<<<dim3(64,32),  256, 0, stream>>>(Wv, Wv_t, 1024, 2048, 1.f);
  conv_t<<<dim3(32,64),  256, 0, stream>>>(Wo, Wo_t, 2048, 1024, 1.f);
  conv_t<<<dim3(128,32), 256, 0, stream>>>(W1, W1_t, 1024, 4096, 1.f);
  conv_t<<<dim3(32,128), 256, 0, stream>>>(W2, W2_t, 4096, 1024, 1.f);

  ln_bf16<<<8192, 256, 0, stream>>>(x, ln1_w, ln1_b, hbuf);

  gemm_nt<<<dim3(8,64),  256, 0, stream>>>(hbuf, Wq_t, 8192, 1024, 1024, 1024, nullptr, qb, nullptr, nullptr, 2);
  gemm_nt<<<dim3(8,64),  256, 0, stream>>>(hbuf, Wk_t, 8192, 1024, 1024, 1024, nullptr, kb, nullptr, nullptr, 2);
  gemm_nt<<<dim3(16,64), 256, 0, stream>>>(hbuf, Wv_t, 8192, 2048, 1024, 1024, nullptr, vb, nullptr, nullptr, 2);

  ret_scores<<<1024, 256, 0, stream>>>(qb, kb, Abuf);
  for (int b = 0; b < 2; ++b){
    const s16* qb_b = qb + (size_t)b*4096*1024;
    const s16* kb_b = kb + (size_t)b*4096*1024;
    const s16* vb_b = vb + (size_t)b*4096*2048;
    const s16* Ab_b = Abuf + (size_t)b*8*64*4096;
    s16* ob_b = ob + (size_t)b*4096*2048;
    ret_state<<<128, 256, 0, stream>>>(kb_b, vb_b, Sbuf);
    ret_out<<<2048, 256, 0, stream>>>(qb_b, vb_b, Ab_b, Sbuf, ob_b);
  }

  gemm_nt<<<dim3(8,64),  256, 0, stream>>>(ob, Wo_t, 8192, 1024, 2048, 2048, x1, nullptr, nullptr, x, 0);
  ln_bf16<<<8192, 256, 0, stream>>>(x1, ln2_w, ln2_b, h2);

  // FFN in two 2048-wide halves (f-buffer 32 MB instead of 64)
  // half 0: out = x1 + b2 + gelu(h2@W1[:, :2048]) @ W2[:2048, :]
  gemm_nt<<<dim3(16,64), 256, 0, stream>>>(h2, W1_t, 8192, 2048, 1024, 1024, nullptr, fb, b1, nullptr, 2|1);
  gemm_nt<<<dim3(8,64),  256, 0, stream>>>(fb, W2_t, 8192, 1024, 2048, 4096, out, nullptr, b2, x1, 0);
  // half 1: out += gelu(h2@W1[:, 2048:]) @ W2[2048:, :]
  gemm_nt<<<dim3(16,64), 256, 0, stream>>>(h2, W1_t + (size_t)2048*1024, 8192, 2048, 1024, 1024, nullptr, fb, b1 + 2048, nullptr, 2|1);
  gemm_nt<<<dim3(8,64),  256, 0, stream>>>(fb, W2_t + 2048, 8192, 1024, 2048, 4096, out, nullptr, nullptr, out, 0);
}

// Round 3
// 931.601 us; speedup vs baseline: 1.3459x; 1.3459x over previous
//
#include <hip/hip_runtime.h>
#include <math.h>

typedef short s16;
typedef __attribute__((ext_vector_type(8))) short short8;
typedef __attribute__((ext_vector_type(4))) float f32x4;

__device__ __forceinline__ float bf2f_lo(unsigned u){ return __builtin_bit_cast(float, u << 16); }
__device__ __forceinline__ float bf2f_hi(unsigned u){ return __builtin_bit_cast(float, u & 0xffff0000u); }
__device__ __forceinline__ float bf2f(unsigned short h){ return __builtin_bit_cast(float, (unsigned)h << 16); }
__device__ __forceinline__ s16 f2bf(float f){
  unsigned u = __builtin_bit_cast(unsigned, f);
  u += 0x7fffu + ((u >> 16) & 1u);
  return (s16)(u >> 16);
}
__device__ __forceinline__ void unpack8(int4 v, float* f){
  unsigned a=(unsigned)v.x, b=(unsigned)v.y, c=(unsigned)v.z, d=(unsigned)v.w;
  f[0]=bf2f_lo(a); f[1]=bf2f_hi(a); f[2]=bf2f_lo(b); f[3]=bf2f_hi(b);
  f[4]=bf2f_lo(c); f[5]=bf2f_hi(c); f[6]=bf2f_lo(d); f[7]=bf2f_hi(d);
}

// ---------------- LayerNorm (fp32 in) -> bf16 out, D=1024, 1 block/row ------
__global__ __launch_bounds__(256) void ln_bf16(const float* __restrict__ x,
                                               const float* __restrict__ w,
                                               const float* __restrict__ b,
                                               s16* __restrict__ out){
  int row = blockIdx.x; int t = threadIdx.x;
  const float* xr = x + (size_t)row * 1024;
  float4 v = *(const float4*)(xr + t*4);
  float s = v.x + v.y + v.z + v.w;
  float ss = v.x*v.x + v.y*v.y + v.z*v.z + v.w*v.w;
  for (int o = 32; o > 0; o >>= 1){ s += __shfl_down(s, o, 64); ss += __shfl_down(ss, o, 64); }
  __shared__ float red[8];
  int wid = t >> 6, lane = t & 63;
  if (lane == 0){ red[wid] = s; red[4+wid] = ss; }
  __syncthreads();
  if (t == 0){
    float S = red[0]+red[1]+red[2]+red[3];
    float SS = red[4]+red[5]+red[6]+red[7];
    red[0] = S * (1.f/1024.f);
    red[1] = SS * (1.f/1024.f);
  }
  __syncthreads();
  float mu = red[0];
  float var = red[1] - mu*mu;
  float rstd = rsqrtf(var + 1e-6f);
  float vv[4] = {v.x, v.y, v.z, v.w};
  short4 o4;
  s16 tmp[4];
  #pragma unroll
  for (int i = 0; i < 4; ++i){
    int c = t*4 + i;
    float val = (vv[i] - mu) * rstd * w[c] + b[c];
    tmp[i] = f2bf(val);
  }
  o4.x = tmp[0]; o4.y = tmp[1]; o4.z = tmp[2]; o4.w = tmp[3];
  *(short4*)(out + (size_t)row*1024 + t*4) = o4;
}

// ---------------- transpose-convert fp32 W[K,N] -> bf16 Wt[N,K], with scale --
__global__ __launch_bounds__(256) void conv_t(const float* __restrict__ W,
                                              s16* __restrict__ Wt,
                                              int K, int N, float scale){
  __shared__ float tile[32][33];
  int n0 = blockIdx.x * 32, k0 = blockIdx.y * 32;
  int tx = threadIdx.x & 31, ty = threadIdx.x >> 5;   // ty 0..7
  #pragma unroll
  for (int i = 0; i < 4; ++i){
    int r = ty + i*8;
    tile[r][tx] = W[(size_t)(k0 + r)*N + n0 + tx];
  }
  __syncthreads();
  #pragma unroll
  for (int i = 0; i < 4; ++i){
    int r = ty + i*8;
    Wt[(size_t)(n0 + r)*K + k0 + tx] = f2bf(tile[tx][r] * scale);
  }
}

// ---------------- bf16 MFMA GEMM:  C[M,N] = A[M,K] @ Bt[N,:]^T  --------------
// Bt row stride = ldb (>= K). flags: bit0 = gelu, bit1 = out bf16
__global__ __launch_bounds__(256,2) void gemm_nt(const s16* __restrict__ A,
                                                 const s16* __restrict__ Bt,
                                                 int M, int N, int K, int ldb,
                                                 float* __restrict__ Cf,
                                                 s16* __restrict__ Cb,
                                                 const float* __restrict__ bias,
                                                 const float* __restrict__ resid,
                                                 int flags){
  __shared__ s16 As[128*40];
  __shared__ s16 Bs[128*40];
  int t = threadIdx.x;
  int m0 = blockIdx.y * 128, n0 = blockIdx.x * 128;
  int w = t >> 6, lane = t & 63;
  int wm = (w >> 1) * 64, wn = (w & 1) * 64;
  int lrow = lane & 15, lq = lane >> 4;
  f32x4 acc[4][4];
  #pragma unroll
  for (int i = 0; i < 4; ++i)
    #pragma unroll
    for (int j = 0; j < 4; ++j) acc[i][j] = (f32x4){0.f,0.f,0.f,0.f};

  const s16* Aptr = A + (size_t)m0 * K;
  const s16* Bptr = Bt + (size_t)n0 * ldb;
  int r0 = t >> 2;            // 0..63
  int kq8 = (t & 3) * 8;      // 0,8,16,24

  for (int k0 = 0; k0 < K; k0 += 32){
    __syncthreads();
    int4 a0 = *(const int4*)(Aptr + (size_t)r0 * K + k0 + kq8);
    int4 a1 = *(const int4*)(Aptr + (size_t)(r0+64) * K + k0 + kq8);
    int4 b0 = *(const int4*)(Bptr + (size_t)r0 * ldb + k0 + kq8);
    int4 b1 = *(const int4*)(Bptr + (size_t)(r0+64) * ldb + k0 + kq8);
    *(int4*)&As[r0*40 + kq8]      = a0;
    *(int4*)&As[(r0+64)*40 + kq8] = a1;
    *(int4*)&Bs[r0*40 + kq8]      = b0;
    *(int4*)&Bs[(r0+64)*40 + kq8] = b1;
    __syncthreads();
    short8 af[4], bfr[4];
    #pragma unroll
    for (int mi = 0; mi < 4; ++mi)
      af[mi] = *(short8*)&As[(wm + mi*16 + lrow)*40 + lq*8];
    #pragma unroll
    for (int ni = 0; ni < 4; ++ni)
      bfr[ni] = *(short8*)&Bs[(wn + ni*16 + lrow)*40 + lq*8];
    #pragma unroll
    for (int mi = 0; mi < 4; ++mi)
      #pragma unroll
      for (int ni = 0; ni < 4; ++ni)
        acc[mi][ni] = __builtin_amdgcn_mfma_f32_16x16x32_bf16(af[mi], bfr[ni], acc[mi][ni], 0, 0, 0);
  }

  bool do_gelu = flags & 1;
  bool out_bf = flags & 2;
  #pragma unroll
  for (int mi = 0; mi < 4; ++mi){
    #pragma unroll
    for (int ni = 0; ni < 4; ++ni){
      int gcol = n0 + wn + ni*16 + lrow;
      float bcol = bias ? bias[gcol] : 0.f;
      int grow_base = m0 + wm + mi*16 + lq*4;
      #pragma unroll
      for (int r = 0; r < 4; ++r){
        int grow = grow_base + r;
        float val = acc[mi][ni][r] + bcol;
        if (do_gelu) val = 0.5f * val * (1.f + erff(val * 0.70710678118654752f));
        if (resid) val += resid[(size_t)grow * N + gcol];
        if (out_bf) Cb[(size_t)grow * N + gcol] = f2bf(val);
        else        Cf[(size_t)grow * N + gcol] = val;
      }
    }
  }
}

// ---------------- retention pass 1: A = (q k^T) * decay-mask (bf16 out) ------
// grid 1024 = bh(16) x chunk(64); q,k bf16 [8192,1024] (q pre-scaled by DK^-0.5)
__global__ __launch_bounds__(256,2) void ret_scores(const s16* __restrict__ q,
                                                    const s16* __restrict__ k,
                                                    s16* __restrict__ Abuf){
  int bi = blockIdx.x;
  int bh = bi & 15, n = bi >> 4;
  int b = bh >> 3, h = bh & 7;
  int t = threadIdx.x;
  __shared__ float qs[64*130];
  __shared__ s16 ks[64*130];
  float log2b = log2f(1.f - exp2f(-5.f - (float)h));
  const s16* qbase = q + ((size_t)(b*4096 + n*64))*1024 + h*128;
  const s16* kbase = k + ((size_t)(b*4096 + n*64))*1024 + h*128;
  #pragma unroll
  for (int i = 0; i < 4; ++i){
    int e = i*2048 + t*8;
    int row = e >> 7, col = e & 127;
    int4 qv = *(const int4*)(qbase + (size_t)row*1024 + col);
    int4 kv = *(const int4*)(kbase + (size_t)row*1024 + col);
    float f[8]; unpack8(qv, f);
    #pragma unroll
    for (int j = 0; j < 8; ++j) qs[row*130 + col + j] = f[j];
    int* kd = (int*)&ks[row*130 + col];
    kd[0] = kv.x; kd[1] = kv.y; kd[2] = kv.z; kd[3] = kv.w;
  }
  __syncthreads();
  int s = t & 63, tw = t >> 6;
  s16* Atile = Abuf + ((size_t)(bh*64 + n))*4096;
  #pragma unroll
  for (int i = 0; i < 16; ++i){
    int tt = i*4 + tw;
    float a = 0.f;
    #pragma unroll 16
    for (int dk = 0; dk < 128; dk += 2){
      float2 q2 = *(const float2*)&qs[tt*130 + dk];
      unsigned kw = *(const unsigned*)&ks[s*130 + dk];
      a += q2.x * bf2f_lo(kw);
      a += q2.y * bf2f_hi(kw);
    }
    int d = tt - s;
    float val = (d >= 0) ? a * exp2f(log2b * (float)d) : 0.f;
    Atile[tt*64 + s] = f2bf(val);
  }
}

// ---------------- retention pass 2a (per batch): per-chunk outer products ----
// grid 512 = h(8) + n(64); U[h][n][128][256] bf16 = sum_s d_k[s]*k[s] (x) v[s]
__global__ __launch_bounds__(256,2) void ret_chunksum(const s16* __restrict__ k,
                                                      const s16* __restrict__ v,
                                                      s16* __restrict__ U){
  int bi = blockIdx.x;
  int h = bi & 7, n = bi >> 3;
  int t = threadIdx.x;
  __shared__ s16 ks[128*72];   // ks[dk][s], d_k decay folded
  __shared__ s16 vs[256*72];   // vs[dv][s]
  float log2b = log2f(1.f - exp2f(-5.f - (float)h));
  const s16* kbase = k + (size_t)(n*64)*1024 + h*128;
  const s16* vbase = v + (size_t)(n*64)*2048 + h*256;
  #pragma unroll
  for (int i = 0; i < 4; ++i){
    int e = i*2048 + t*8;
    int s = e >> 7, dk = e & 127;
    int4 kv = *(const int4*)(kbase + (size_t)s*1024 + dk);
    float f[8]; unpack8(kv, f);
    float dec = exp2f(log2b * (float)(63 - s));
    #pragma unroll
    for (int j = 0; j < 8; ++j) ks[(dk+j)*72 + s] = f2bf(f[j]*dec);
  }
  #pragma unroll
  for (int i = 0; i < 8; ++i){
    int e = i*2048 + t*8;
    int s = e >> 8, dv = e & 255;
    int4 vv = *(const int4*)(vbase + (size_t)s*2048 + dv);
    s16 tmp[8]; *(int4*)tmp = vv;
    #pragma unroll
    for (int j = 0; j < 8; ++j) vs[(dv+j)*72 + s] = tmp[j];
  }
  __syncthreads();
  int w = t >> 6, lane = t & 63;
  int m0w = (w & 1)*64, n0w = (w >> 1)*128;
  int lrow = lane & 15, lq = lane >> 4;
  f32x4 acc[4][8];
  #pragma unroll
  for (int mi = 0; mi < 4; ++mi)
    #pragma unroll
    for (int ni = 0; ni < 8; ++ni) acc[mi][ni] = (f32x4){0.f,0.f,0.f,0.f};
  #pragma unroll
  for (int kk = 0; kk < 64; kk += 32){
    short8 af[4], bfr[8];
    #pragma unroll
    for (int mi = 0; mi < 4; ++mi)
      af[mi] = *(short8*)&ks[(m0w + mi*16 + lrow)*72 + kk + lq*8];
    #pragma unroll
    for (int ni = 0; ni < 8; ++ni)
      bfr[ni] = *(short8*)&vs[(n0w + ni*16 + lrow)*72 + kk + lq*8];
    #pragma unroll
    for (int mi = 0; mi < 4; ++mi)
      #pragma unroll
      for (int ni = 0; ni < 8; ++ni)
        acc[mi][ni] = __builtin_amdgcn_mfma_f32_16x16x32_bf16(af[mi], bfr[ni], acc[mi][ni], 0, 0, 0);
  }
  s16* Ub = U + ((size_t)(h*64 + n))*32768;
  #pragma unroll
  for (int mi = 0; mi < 4; ++mi)
    #pragma unroll
    for (int ni = 0; ni < 8; ++ni)
      #pragma unroll
      for (int r = 0; r < 4; ++r){
        int row = m0w + mi*16 + lq*4 + r;
        int col = n0w + ni*16 + lrow;
        Ub[(size_t)row*256 + col] = f2bf(acc[mi][ni][r]);
      }
}

// ---------------- retention pass 2b (per batch): in-place decay prefix scan --
// grid 128; thread owns 8 dv of one (h,dk); US[n] : U in, S out (state BEFORE n)
__global__ __launch_bounds__(256) void ret_scan(s16* __restrict__ US){
  int tid = blockIdx.x*256 + threadIdx.x;       // 32768 threads
  int h = tid >> 12;
  int rem = tid & 4095;
  int dk = rem >> 5, dv0 = (rem & 31)*8;
  float log2b = log2f(1.f - exp2f(-5.f - (float)h));
  float dc = exp2f(log2b * 64.f);
  s16* base = US + (size_t)h*64*32768 + (size_t)dk*256 + dv0;
  float acc[8] = {0.f,0.f,0.f,0.f,0.f,0.f,0.f,0.f};
  #pragma unroll 4
  for (int n = 0; n < 64; ++n){
    s16* p = base + (size_t)n*32768;
    int4 u4 = *(const int4*)p;
    float uf[8]; unpack8(u4, uf);
    s16 sb[8];
    #pragma unroll
    for (int j = 0; j < 8; ++j) sb[j] = f2bf(acc[j]);
    *(int4*)p = *(int4*)sb;
    #pragma unroll
    for (int j = 0; j < 8; ++j) acc[j] = acc[j]*dc + uf[j];
  }
}

// ---------------- retention pass 3 (per batch): o = A@v + d_q * (q @ S) ------
// grid 2048 = h(8) x chunk(64) x jb(4); o bf16 [4096, 2048]
__global__ __launch_bounds__(256,2) void ret_out(const s16* __restrict__ q,
                                                 const s16* __restrict__ v,
                                                 const s16* __restrict__ Abuf,
                                                 const s16* __restrict__ S,
                                                 s16* __restrict__ o){
  int bi = blockIdx.x;
  int jb = bi & 3, n = (bi >> 2) & 63, h = bi >> 8;
  int dv0 = jb * 64;
  int t = threadIdx.x;
  int j = t & 63, tg = t >> 6;
  float log2b = log2f(1.f - exp2f(-5.f - (float)h));
  __shared__ float qs[64*132];   // d_q-prescaled, fp32
  __shared__ float As[64*68];
  __shared__ s16 vsb[64*68];

  const s16* qbase = q + ((size_t)(n*64))*1024 + h*128;
  const s16* vbase = v + ((size_t)(n*64))*2048 + h*256 + dv0;
  const s16* Atile = Abuf + ((size_t)(h*64 + n))*4096;

  #pragma unroll
  for (int i = 0; i < 4; ++i){
    int e = i*2048 + t*8;
    int row = e >> 7, col = e & 127;
    int4 qv = *(const int4*)(qbase + (size_t)row*1024 + col);
    float f[8]; unpack8(qv, f);
    float dq = exp2f(log2b * (float)(row + 1));
    #pragma unroll
    for (int jj = 0; jj < 8; ++jj) qs[row*132 + col + jj] = f[jj] * dq;
  }
  #pragma unroll
  for (int i = 0; i < 2; ++i){
    int e = i*2048 + t*8;
    int tt = e >> 6, s = e & 63;
    int4 a8 = *(const int4*)(Atile + e);
    float f[8]; unpack8(a8, f);
    #pragma unroll
    for (int jj = 0; jj < 8; ++jj) As[tt*68 + s + jj] = f[jj];
  }
  #pragma unroll
  for (int i = 0; i < 2; ++i){
    int e = i*2048 + t*8;
    int sv = e >> 6, c = e & 63;
    int4 vv = *(const int4*)(vbase + (size_t)sv*2048 + c);
    int* vd = (int*)&vsb[sv*68 + c];
    vd[0] = vv.x; vd[1] = vv.y; vd[2] = vv.z; vd[3] = vv.w;
  }
  __syncthreads();

  float acc[16];
  #pragma unroll
  for (int i = 0; i < 16; ++i) acc[i] = 0.f;

  // A @ v
  for (int s = 0; s < 64; s += 4){
    float vv[4];
    #pragma unroll
    for (int u = 0; u < 4; ++u) vv[u] = bf2f((unsigned short)vsb[(s+u)*68 + j]);
    #pragma unroll
    for (int tt = 0; tt < 16; ++tt){
      float4 a4 = *(const float4*)&As[(tg*16 + tt)*68 + s];
      acc[tt] += a4.x*vv[0] + a4.y*vv[1] + a4.z*vv[2] + a4.w*vv[3];
    }
  }
  // d_q*q @ S
  const s16* Sb = S + ((size_t)(h*64 + n))*32768 + dv0 + j;
  for (int dk = 0; dk < 128; dk += 4){
    float sv[4];
    #pragma unroll
    for (int u = 0; u < 4; ++u) sv[u] = bf2f((unsigned short)Sb[(size_t)(dk+u)*256]);
    #pragma unroll
    for (int tt = 0; tt < 16; ++tt){
      float4 q4 = *(const float4*)&qs[(tg*16 + tt)*132 + dk];
      acc[tt] += q4.x*sv[0] + q4.y*sv[1] + q4.z*sv[2] + q4.w*sv[3];
    }
  }
  s16* obase = o + ((size_t)(n*64))*2048 + h*256 + dv0 + j;
  #pragma unroll
  for (int tt = 0; tt < 16; ++tt){
    int row = tg*16 + tt;
    obase[(size_t)row*2048] = f2bf(acc[tt]);
  }
}

extern "C" void kernel_launch(void* const* d_in, const int* in_sizes, int n_in,
                              void* d_out, int out_size, void* d_ws, size_t ws_size,
                              hipStream_t stream) {
  (void)in_sizes; (void)n_in; (void)out_size; (void)ws_size;
  const float* x     = (const float*)d_in[0];
  const float* ln1_w = (const float*)d_in[1];
  const float* ln1_b = (const float*)d_in[2];
  const float* Wq    = (const float*)d_in[3];
  const float* Wk    = (const float*)d_in[4];
  const float* Wv    = (const float*)d_in[5];
  const float* Wo    = (const float*)d_in[6];
  const float* ln2_w = (const float*)d_in[7];
  const float* ln2_b = (const float*)d_in[8];
  const float* W1    = (const float*)d_in[9];
  const float* b1    = (const float*)d_in[10];
  const float* W2    = (const float*)d_in[11];
  const float* b2    = (const float*)d_in[12];
  float* out = (float*)d_out;
  char* ws = (char*)d_ws;

  // ---- static arena, peak 172 MB (lifetime-aliased) ----
  const size_t MB = 1ull << 20;
  s16* Wq_t = (s16*)(ws + 0*MB);     // [0,2)
  s16* Wk_t = (s16*)(ws + 2*MB);     // [2,4)
  s16* Wv_t = (s16*)(ws + 4*MB);     // [4,8)
  s16* Wo_t = (s16*)(ws + 8*MB);     // [8,12)
  s16* W1_t = (s16*)(ws + 12*MB);    // [12,20)
  s16* W2_t = (s16*)(ws + 20*MB);    // [20,28)
  s16* hbuf = (s16*)(ws + 28*MB);    // [28,44)  dead after QKV gemms
  s16* Abuf = (s16*)(ws + 28*MB);    // [28,36)  bf16 scores, alias dead hbuf
  s16* h2   = (s16*)(ws + 28*MB);    // [28,44)  alias dead Abuf (post-retention)
  s16* qb   = (s16*)(ws + 44*MB);    // [44,60)  dead after ret_out(b1)
  s16* kb   = (s16*)(ws + 60*MB);    // [60,76)  dead after ret_chunksum(b1)
  s16* vb   = (s16*)(ws + 76*MB);    // [76,108) dead after ret_out(b1)
  float* x1 = (float*)(ws + 44*MB);  // [44,76)  alias dead qb+kb (post-retention)
  s16* fb   = (s16*)(ws + 76*MB);    // [76,108) alias dead vb (FFN half, 8192x2048)
  s16* US   = (s16*)(ws + 108*MB);   // [108,140) bf16 per-batch U->S (in-place scan)
  s16* ob   = (s16*)(ws + 140*MB);   // [140,172)

  // weight transpose-convert (DK^-0.5 folded into Wq)
  conv_t<<<dim3(32,32),  256, 0, stream>>>(Wq, Wq_t, 1024, 1024, 0.08838834764831845f);
  conv_t<<<dim3(32,32),  256, 0, stream>>>(Wk, Wk_t, 1024, 1024, 1.f);
  conv_t<<<dim3(64,32),  256, 0, stream>>>(Wv, Wv_t, 1024, 2048, 1.f);
  conv_t<<<dim3(32,64),  256, 0, stream>>>(Wo, Wo_t, 2048, 1024, 1.f);
  conv_t<<<dim3(128,32), 256, 0, stream>>>(W1, W1_t, 1024, 4096, 1.f);
  conv_t<<<dim3(32,128), 256, 0, stream>>>(W2, W2_t, 4096, 1024, 1.f);

  ln_bf16<<<8192, 256, 0, stream>>>(x, ln1_w, ln1_b, hbuf);

  gemm_nt<<<dim3(8,64),  256, 0, stream>>>(hbuf, Wq_t, 8192, 1024, 1024, 1024, nullptr, qb, nullptr, nullptr, 2);
  gemm_nt<<<dim3(8,64),  256, 0, stream>>>(hbuf, Wk_t, 8192, 1024, 1024, 1024, nullptr, kb, nullptr, nullptr, 2);
  gemm_nt<<<dim3(16,64), 256, 0, stream>>>(hbuf, Wv_t, 8192, 2048, 1024, 1024, nullptr, vb, nullptr, nullptr, 2);

  ret_scores<<<1024, 256, 0, stream>>>(qb, kb, Abuf);
  for (int b = 0; b < 2; ++b){
    const s16* qb_b = qb + (size_t)b*4096*1024;
    const s16* kb_b = kb + (size_t)b*4096*1024;
    const s16* vb_b = vb + (size_t)b*4096*2048;
    const s16* Ab_b = Abuf + (size_t)b*8*64*4096;
    s16* ob_b = ob + (size_t)b*4096*2048;
    ret_chunksum<<<512, 256, 0, stream>>>(kb_b, vb_b, US);
    ret_scan<<<128, 256, 0, stream>>>(US);
    ret_out<<<2048, 256, 0, stream>>>(qb_b, vb_b, Ab_b, US, ob_b);
  }

  gemm_nt<<<dim3(8,64),  256, 0, stream>>>(ob, Wo_t, 8192, 1024, 2048, 2048, x1, nullptr, nullptr, x, 0);
  ln_bf16<<<8192, 256, 0, stream>>>(x1, ln2_w, ln2_b, h2);

  // FFN in two 2048-wide halves (f-buffer 32 MB instead of 64)
  gemm_nt<<<dim3(16,64), 256, 0, stream>>>(h2, W1_t, 8192, 2048, 1024, 1024, nullptr, fb, b1, nullptr, 2|1);
  gemm_nt<<<dim3(8,64),  256, 0, stream>>>(fb, W2_t, 8192, 1024, 2048, 4096, out, nullptr, b2, x1, 0);
  gemm_nt<<<dim3(16,64), 256, 0, stream>>>(h2, W1_t + (size_t)2048*1024, 8192, 2048, 1024, 1024, nullptr, fb, b1 + 2048, nullptr, 2|1);
  gemm_nt<<<dim3(8,64),  256, 0, stream>>>(fb, W2_t + 2048, 8192, 1024, 2048, 4096, out, nullptr, nullptr, out, 0);
}

// Round 4
// 720.012 us; speedup vs baseline: 1.7415x; 1.2939x over previous
//
#include <hip/hip_runtime.h>
#include <math.h>

typedef short s16;
typedef __attribute__((ext_vector_type(8))) short short8;
typedef __attribute__((ext_vector_type(4))) float f32x4;

__device__ __forceinline__ float bf2f_lo(unsigned u){ return __builtin_bit_cast(float, u << 16); }
__device__ __forceinline__ float bf2f_hi(unsigned u){ return __builtin_bit_cast(float, u & 0xffff0000u); }
__device__ __forceinline__ float bf2f(unsigned short h){ return __builtin_bit_cast(float, (unsigned)h << 16); }
__device__ __forceinline__ s16 f2bf(float f){
  unsigned u = __builtin_bit_cast(unsigned, f);
  u += 0x7fffu + ((u >> 16) & 1u);
  return (s16)(u >> 16);
}
__device__ __forceinline__ void unpack8(int4 v, float* f){
  unsigned a=(unsigned)v.x, b=(unsigned)v.y, c=(unsigned)v.z, d=(unsigned)v.w;
  f[0]=bf2f_lo(a); f[1]=bf2f_hi(a); f[2]=bf2f_lo(b); f[3]=bf2f_hi(b);
  f[4]=bf2f_lo(c); f[5]=bf2f_hi(c); f[6]=bf2f_lo(d); f[7]=bf2f_hi(d);
}
// async global->LDS 16B: lds dest is wave-uniform base + lane*16
__device__ __forceinline__ void gl2lds16(const s16* g, s16* l){
  __builtin_amdgcn_global_load_lds((const __attribute__((address_space(1))) void*)g,
                                   (__attribute__((address_space(3))) void*)l, 16, 0, 0);
}

// ---------------- LayerNorm (fp32 in) -> bf16 out, D=1024, 1 block/row ------
__global__ __launch_bounds__(256) void ln_bf16(const float* __restrict__ x,
                                               const float* __restrict__ w,
                                               const float* __restrict__ b,
                                               s16* __restrict__ out){
  int row = blockIdx.x; int t = threadIdx.x;
  const float* xr = x + (size_t)row * 1024;
  float4 v = *(const float4*)(xr + t*4);
  float s = v.x + v.y + v.z + v.w;
  float ss = v.x*v.x + v.y*v.y + v.z*v.z + v.w*v.w;
  for (int o = 32; o > 0; o >>= 1){ s += __shfl_down(s, o, 64); ss += __shfl_down(ss, o, 64); }
  __shared__ float red[8];
  int wid = t >> 6, lane = t & 63;
  if (lane == 0){ red[wid] = s; red[4+wid] = ss; }
  __syncthreads();
  if (t == 0){
    float S = red[0]+red[1]+red[2]+red[3];
    float SS = red[4]+red[5]+red[6]+red[7];
    red[0] = S * (1.f/1024.f);
    red[1] = SS * (1.f/1024.f);
  }
  __syncthreads();
  float mu = red[0];
  float var = red[1] - mu*mu;
  float rstd = rsqrtf(var + 1e-6f);
  float vv[4] = {v.x, v.y, v.z, v.w};
  short4 o4;
  s16 tmp[4];
  #pragma unroll
  for (int i = 0; i < 4; ++i){
    int c = t*4 + i;
    float val = (vv[i] - mu) * rstd * w[c] + b[c];
    tmp[i] = f2bf(val);
  }
  o4.x = tmp[0]; o4.y = tmp[1]; o4.z = tmp[2]; o4.w = tmp[3];
  *(short4*)(out + (size_t)row*1024 + t*4) = o4;
}

// ---------------- transpose-convert fp32 W[K,N] -> bf16 Wt[N,K], with scale --
__global__ __launch_bounds__(256) void conv_t(const float* __restrict__ W,
                                              s16* __restrict__ Wt,
                                              int K, int N, float scale){
  __shared__ float tile[32][33];
  int n0 = blockIdx.x * 32, k0 = blockIdx.y * 32;
  int tx = threadIdx.x & 31, ty = threadIdx.x >> 5;   // ty 0..7
  #pragma unroll
  for (int i = 0; i < 4; ++i){
    int r = ty + i*8;
    tile[r][tx] = W[(size_t)(k0 + r)*N + n0 + tx];
  }
  __syncthreads();
  #pragma unroll
  for (int i = 0; i < 4; ++i){
    int r = ty + i*8;
    Wt[(size_t)(n0 + r)*K + k0 + tx] = f2bf(tile[tx][r] * scale);
  }
}

// ---------------- bf16 MFMA GEMM (m97-style):  C = A[M,K] @ Bt[N,:]^T  -------
// Bt row stride = ldb. flags: bit0 = gelu, bit1 = out bf16
__global__ __launch_bounds__(256,2) void gemm_nt(const s16* __restrict__ A,
                                                 const s16* __restrict__ Bt,
                                                 int M, int N, int K, int ldb,
                                                 float* __restrict__ Cf,
                                                 s16* __restrict__ Cb,
                                                 const float* __restrict__ bias,
                                                 const float* __restrict__ resid,
                                                 int flags){
  __shared__ s16 As[128*32];
  __shared__ s16 Bs[128*32];
  int t = threadIdx.x;
  int m0 = blockIdx.y * 128, n0 = blockIdx.x * 128;
  int w = t >> 6, lane = t & 63;
  int wm = (w >> 1) * 64, wn = (w & 1) * 64;
  int lrow = lane & 15, lq = lane >> 4;
  f32x4 acc[4][4];
  #pragma unroll
  for (int i = 0; i < 4; ++i)
    #pragma unroll
    for (int j = 0; j < 4; ++j) acc[i][j] = (f32x4){0.f,0.f,0.f,0.f};

  // per-lane global src (row = t>>2, kquad = t&3); lds dest wave-uniform
  const s16* Ag = A  + (size_t)(m0 + (t>>2)) * K   + (t&3)*8;
  const s16* Bg = Bt + (size_t)(n0 + (t>>2)) * ldb + (t&3)*8;
  s16* lA0 = As + w*512;          // +w*1024 bytes
  s16* lA1 = As + 2048 + w*512;
  s16* lB0 = Bs + w*512;
  s16* lB1 = Bs + 2048 + w*512;

  for (int k0 = 0; k0 < K; k0 += 32){
    __syncthreads();
    gl2lds16(Ag + k0, lA0);
    gl2lds16(Ag + (size_t)64*K + k0, lA1);
    gl2lds16(Bg + k0, lB0);
    gl2lds16(Bg + (size_t)64*ldb + k0, lB1);
    __syncthreads();
    short8 af[4], bfr[4];
    #pragma unroll
    for (int mi = 0; mi < 4; ++mi)
      af[mi] = *(short8*)&As[(wm + mi*16 + lrow)*32 + lq*8];
    #pragma unroll
    for (int ni = 0; ni < 4; ++ni)
      bfr[ni] = *(short8*)&Bs[(wn + ni*16 + lrow)*32 + lq*8];
    #pragma unroll
    for (int mi = 0; mi < 4; ++mi)
      #pragma unroll
      for (int ni = 0; ni < 4; ++ni)
        acc[mi][ni] = __builtin_amdgcn_mfma_f32_16x16x32_bf16(af[mi], bfr[ni], acc[mi][ni], 0, 0, 0);
  }

  bool do_gelu = flags & 1;
  bool out_bf = flags & 2;
  #pragma unroll
  for (int mi = 0; mi < 4; ++mi){
    #pragma unroll
    for (int ni = 0; ni < 4; ++ni){
      int gcol = n0 + wn + ni*16 + lrow;
      float bcol = bias ? bias[gcol] : 0.f;
      int grow_base = m0 + wm + mi*16 + lq*4;
      #pragma unroll
      for (int r = 0; r < 4; ++r){
        int grow = grow_base + r;
        float val = acc[mi][ni][r] + bcol;
        if (do_gelu) val = 0.5f * val * (1.f + erff(val * 0.70710678118654752f));
        if (resid) val += resid[(size_t)grow * N + gcol];
        if (out_bf) Cb[(size_t)grow * N + gcol] = f2bf(val);
        else        Cf[(size_t)grow * N + gcol] = val;
      }
    }
  }
}

// ---------------- retention 2a (per batch): U_t[dv][dk] = (d_k*k (x) v)^T ----
// grid 512 = h(8) + n(64); output transposed [h][n][256][128] bf16
__global__ __launch_bounds__(256,2) void ret_chunksum(const s16* __restrict__ k,
                                                      const s16* __restrict__ v,
                                                      s16* __restrict__ U){
  int bi = blockIdx.x;
  int h = bi & 7, n = bi >> 3;
  int t = threadIdx.x;
  __shared__ s16 ks[128*72];   // ks[dk][s], d_k decay folded
  __shared__ s16 vs[256*72];   // vs[dv][s]
  float log2b = log2f(1.f - exp2f(-5.f - (float)h));
  const s16* kbase = k + (size_t)(n*64)*1024 + h*128;
  const s16* vbase = v + (size_t)(n*64)*2048 + h*256;
  #pragma unroll
  for (int i = 0; i < 4; ++i){
    int e = i*2048 + t*8;
    int s = e >> 7, dk = e & 127;
    int4 kv = *(const int4*)(kbase + (size_t)s*1024 + dk);
    float f[8]; unpack8(kv, f);
    float dec = exp2f(log2b * (float)(63 - s));
    #pragma unroll
    for (int j = 0; j < 8; ++j) ks[(dk+j)*72 + s] = f2bf(f[j]*dec);
  }
  #pragma unroll
  for (int i = 0; i < 8; ++i){
    int e = i*2048 + t*8;
    int s = e >> 8, dv = e & 255;
    int4 vv = *(const int4*)(vbase + (size_t)s*2048 + dv);
    s16 tmp[8]; *(int4*)tmp = vv;
    #pragma unroll
    for (int j = 0; j < 8; ++j) vs[(dv+j)*72 + s] = tmp[j];
  }
  __syncthreads();
  int w = t >> 6, lane = t & 63;
  int m0w = w*64;   // dv rows, 4 tiles per wave
  int lrow = lane & 15, lq = lane >> 4;
  f32x4 acc[4][8];
  #pragma unroll
  for (int mi = 0; mi < 4; ++mi)
    #pragma unroll
    for (int ni = 0; ni < 8; ++ni) acc[mi][ni] = (f32x4){0.f,0.f,0.f,0.f};
  #pragma unroll
  for (int kk = 0; kk < 64; kk += 32){
    short8 af[4], bfr[8];
    #pragma unroll
    for (int mi = 0; mi < 4; ++mi)
      af[mi] = *(short8*)&vs[(m0w + mi*16 + lrow)*72 + kk + lq*8];
    #pragma unroll
    for (int ni = 0; ni < 8; ++ni)
      bfr[ni] = *(short8*)&ks[(ni*16 + lrow)*72 + kk + lq*8];
    #pragma unroll
    for (int mi = 0; mi < 4; ++mi)
      #pragma unroll
      for (int ni = 0; ni < 8; ++ni)
        acc[mi][ni] = __builtin_amdgcn_mfma_f32_16x16x32_bf16(af[mi], bfr[ni], acc[mi][ni], 0, 0, 0);
  }
  s16* Ub = U + ((size_t)(h*64 + n))*32768;
  #pragma unroll
  for (int mi = 0; mi < 4; ++mi)
    #pragma unroll
    for (int ni = 0; ni < 8; ++ni)
      #pragma unroll
      for (int r = 0; r < 4; ++r){
        int row = m0w + mi*16 + lq*4 + r;   // dv
        int col = ni*16 + lrow;             // dk
        Ub[(size_t)row*128 + col] = f2bf(acc[mi][ni][r]);
      }
}

// ---------------- retention 2b (per batch): in-place decay prefix scan -------
// thread owns 8 dk of one (h,dv); US[n]: U in, S out (state BEFORE chunk n)
__global__ __launch_bounds__(256) void ret_scan(s16* __restrict__ US){
  int tid = blockIdx.x*256 + threadIdx.x;       // 32768 threads
  int h = tid >> 12;
  int rem = tid & 4095;
  int dv = rem >> 4, dk0 = (rem & 15)*8;
  float log2b = log2f(1.f - exp2f(-5.f - (float)h));
  float dc = exp2f(log2b * 64.f);
  s16* base = US + (size_t)h*64*32768 + (size_t)dv*128 + dk0;
  float acc[8] = {0.f,0.f,0.f,0.f,0.f,0.f,0.f,0.f};
  #pragma unroll 4
  for (int n = 0; n < 64; ++n){
    s16* p = base + (size_t)n*32768;
    int4 u4 = *(const int4*)p;
    float uf[8]; unpack8(u4, uf);
    s16 sb[8];
    #pragma unroll
    for (int j = 0; j < 8; ++j) sb[j] = f2bf(acc[j]);
    *(int4*)p = *(int4*)sb;
    #pragma unroll
    for (int j = 0; j < 8; ++j) acc[j] = acc[j]*dc + uf[j];
  }
}

// ---------------- retention fused (per batch): O = mask(qk^T)@v + dq*(q@S) ---
// grid 512 = h(8) + n(64). q,k,v bf16 row-major; S_t [h][n][dv 256][dk 128] bf16
__global__ __launch_bounds__(256,2) void ret_attn(const s16* __restrict__ q,
                                                  const s16* __restrict__ k,
                                                  const s16* __restrict__ v,
                                                  const s16* __restrict__ S,
                                                  s16* __restrict__ o){
  int bi = blockIdx.x;
  int h = bi & 7, n = bi >> 3;
  int t = threadIdx.x;
  int w = t >> 6, lane = t & 63;
  int lrow = lane & 15, lq = lane >> 4;
  float log2b = log2f(1.f - exp2f(-5.f - (float)h));
  __shared__ s16 As[64*72];    // masked scores, A-operand staging
  __shared__ s16 vs[256*72];   // v^T [dv][s]

  // stage v transposed
  const s16* vbase = v + (size_t)(n*64)*2048 + h*256;
  #pragma unroll
  for (int i = 0; i < 8; ++i){
    int e = i*2048 + t*8;
    int s = e >> 8, dv = e & 255;
    int4 vv = *(const int4*)(vbase + (size_t)s*2048 + dv);
    s16 tmp[8]; *(int4*)tmp = vv;
    #pragma unroll
    for (int j = 0; j < 8; ++j) vs[(dv+j)*72 + s] = tmp[j];
  }

  // phase 1: wave w computes A[:, 16w:16w+16] = q @ k^T, masked
  const s16* qbase = q + (size_t)(n*64)*1024 + h*128;
  const s16* kbase = k + (size_t)(n*64)*1024 + h*128;
  short8 qf[4][4];   // [row-tile][kstep], reused in phase 2
  #pragma unroll
  for (int ti = 0; ti < 4; ++ti)
    #pragma unroll
    for (int c = 0; c < 4; ++c)
      qf[ti][c] = *(const short8*)(qbase + (size_t)(ti*16 + lrow)*1024 + c*32 + lq*8);
  short8 kf[4];
  #pragma unroll
  for (int c = 0; c < 4; ++c)
    kf[c] = *(const short8*)(kbase + (size_t)(16*w + lrow)*1024 + c*32 + lq*8);
  #pragma unroll
  for (int ti = 0; ti < 4; ++ti){
    f32x4 acc_a = (f32x4){0.f,0.f,0.f,0.f};
    #pragma unroll
    for (int c = 0; c < 4; ++c)
      acc_a = __builtin_amdgcn_mfma_f32_16x16x32_bf16(qf[ti][c], kf[c], acc_a, 0, 0, 0);
    #pragma unroll
    for (int r = 0; r < 4; ++r){
      int ti_idx = ti*16 + lq*4 + r;
      int s_idx = 16*w + lrow;
      int d = ti_idx - s_idx;
      float val = (d >= 0) ? acc_a[r] * exp2f(log2b * (float)d) : 0.f;
      As[ti_idx*72 + s_idx] = f2bf(val);
    }
  }
  __syncthreads();

  // phase 2: wave w owns dv cols [64w, 64w+64)
  f32x4 acc[4][4];
  #pragma unroll
  for (int mi = 0; mi < 4; ++mi)
    #pragma unroll
    for (int nj = 0; nj < 4; ++nj) acc[mi][nj] = (f32x4){0.f,0.f,0.f,0.f};

  // q @ S  (K = 128)
  const s16* Sbase = S + ((size_t)(h*64 + n)*256 + w*64)*128;
  #pragma unroll
  for (int c = 0; c < 4; ++c){
    short8 bf[4];
    #pragma unroll
    for (int nj = 0; nj < 4; ++nj)
      bf[nj] = *(const short8*)(Sbase + (size_t)(nj*16 + lrow)*128 + c*32 + lq*8);
    #pragma unroll
    for (int mi = 0; mi < 4; ++mi)
      #pragma unroll
      for (int nj = 0; nj < 4; ++nj)
        acc[mi][nj] = __builtin_amdgcn_mfma_f32_16x16x32_bf16(qf[mi][c], bf[nj], acc[mi][nj], 0, 0, 0);
  }
  // scale by d_q = b^(row+1)  (per C/D-layout row)
  #pragma unroll
  for (int mi = 0; mi < 4; ++mi){
    #pragma unroll
    for (int r = 0; r < 4; ++r){
      float dq = exp2f(log2b * (float)(mi*16 + lq*4 + r + 1));
      #pragma unroll
      for (int nj = 0; nj < 4; ++nj) acc[mi][nj][r] *= dq;
    }
  }
  // A @ v  (K = 64)
  #pragma unroll
  for (int c = 0; c < 2; ++c){
    short8 af[4], bf[4];
    #pragma unroll
    for (int mi = 0; mi < 4; ++mi)
      af[mi] = *(short8*)&As[(mi*16 + lrow)*72 + c*32 + lq*8];
    #pragma unroll
    for (int nj = 0; nj < 4; ++nj)
      bf[nj] = *(short8*)&vs[(w*64 + nj*16 + lrow)*72 + c*32 + lq*8];
    #pragma unroll
    for (int mi = 0; mi < 4; ++mi)
      #pragma unroll
      for (int nj = 0; nj < 4; ++nj)
        acc[mi][nj] = __builtin_amdgcn_mfma_f32_16x16x32_bf16(af[mi], bf[nj], acc[mi][nj], 0, 0, 0);
  }
  // write O
  s16* obase = o + (size_t)(n*64)*2048 + h*256;
  #pragma unroll
  for (int mi = 0; mi < 4; ++mi)
    #pragma unroll
    for (int nj = 0; nj < 4; ++nj)
      #pragma unroll
      for (int r = 0; r < 4; ++r){
        int row = mi*16 + lq*4 + r;
        int col = w*64 + nj*16 + lrow;
        obase[(size_t)row*2048 + col] = f2bf(acc[mi][nj][r]);
      }
}

extern "C" void kernel_launch(void* const* d_in, const int* in_sizes, int n_in,
                              void* d_out, int out_size, void* d_ws, size_t ws_size,
                              hipStream_t stream) {
  (void)in_sizes; (void)n_in; (void)out_size; (void)ws_size;
  const float* x     = (const float*)d_in[0];
  const float* ln1_w = (const float*)d_in[1];
  const float* ln1_b = (const float*)d_in[2];
  const float* Wq    = (const float*)d_in[3];
  const float* Wk    = (const float*)d_in[4];
  const float* Wv    = (const float*)d_in[5];
  const float* Wo    = (const float*)d_in[6];
  const float* ln2_w = (const float*)d_in[7];
  const float* ln2_b = (const float*)d_in[8];
  const float* W1    = (const float*)d_in[9];
  const float* b1    = (const float*)d_in[10];
  const float* W2    = (const float*)d_in[11];
  const float* b2    = (const float*)d_in[12];
  float* out = (float*)d_out;
  char* ws = (char*)d_ws;

  // ---- static arena, peak 172 MB (lifetime-aliased) ----
  const size_t MB = 1ull << 20;
  s16* Wq_t = (s16*)(ws + 0*MB);     // [0,2)
  s16* Wk_t = (s16*)(ws + 2*MB);     // [2,4)
  s16* Wv_t = (s16*)(ws + 4*MB);     // [4,8)
  s16* Wo_t = (s16*)(ws + 8*MB);     // [8,12)
  s16* W1_t = (s16*)(ws + 12*MB);    // [12,20)
  s16* W2_t = (s16*)(ws + 20*MB);    // [20,28)
  s16* hbuf = (s16*)(ws + 28*MB);    // [28,44)  dead after QKV gemms
  s16* h2   = (s16*)(ws + 28*MB);    // [28,44)  alias dead hbuf (post-retention)
  s16* qb   = (s16*)(ws + 44*MB);    // [44,60)  dead after ret_attn(b1)
  s16* kb   = (s16*)(ws + 60*MB);    // [60,76)  dead after ret_attn(b1)
  s16* vb   = (s16*)(ws + 76*MB);    // [76,108) dead after ret_attn(b1)
  float* x1 = (float*)(ws + 44*MB);  // [44,76)  alias dead qb+kb (post-retention)
  s16* fb   = (s16*)(ws + 76*MB);    // [76,108) alias dead vb (FFN half, 8192x2048)
  s16* US   = (s16*)(ws + 108*MB);   // [108,140) bf16 per-batch U->S (in-place scan)
  s16* ob   = (s16*)(ws + 140*MB);   // [140,172)

  // weight transpose-convert (DK^-0.5 folded into Wq)
  conv_t<<<dim3(32,32),  256, 0, stream>>>(Wq, Wq_t, 1024, 1024, 0.08838834764831845f);
  conv_t<<<dim3(32,32),  256, 0, stream>>>(Wk, Wk_t, 1024, 1024, 1.f);
  conv_t<<<dim3(64,32),  256, 0, stream>>>(Wv, Wv_t, 1024, 2048, 1.f);
  conv_t<<<dim3(32,64),  256, 0, stream>>>(Wo, Wo_t, 2048, 1024, 1.f);
  conv_t<<<dim3(128,32), 256, 0, stream>>>(W1, W1_t, 1024, 4096, 1.f);
  conv_t<<<dim3(32,128), 256, 0, stream>>>(W2, W2_t, 4096, 1024, 1.f);

  ln_bf16<<<8192, 256, 0, stream>>>(x, ln1_w, ln1_b, hbuf);

  gemm_nt<<<dim3(8,64),  256, 0, stream>>>(hbuf, Wq_t, 8192, 1024, 1024, 1024, nullptr, qb, nullptr, nullptr, 2);
  gemm_nt<<<dim3(8,64),  256, 0, stream>>>(hbuf, Wk_t, 8192, 1024, 1024, 1024, nullptr, kb, nullptr, nullptr, 2);
  gemm_nt<<<dim3(16,64), 256, 0, stream>>>(hbuf, Wv_t, 8192, 2048, 1024, 1024, nullptr, vb, nullptr, nullptr, 2);

  for (int b = 0; b < 2; ++b){
    const s16* qb_b = qb + (size_t)b*4096*1024;
    const s16* kb_b = kb + (size_t)b*4096*1024;
    const s16* vb_b = vb + (size_t)b*4096*2048;
    s16* ob_b = ob + (size_t)b*4096*2048;
    ret_chunksum<<<512, 256, 0, stream>>>(kb_b, vb_b, US);
    ret_scan<<<128, 256, 0, stream>>>(US);
    ret_attn<<<512, 256, 0, stream>>>(qb_b, kb_b, vb_b, US, ob_b);
  }

  gemm_nt<<<dim3(8,64),  256, 0, stream>>>(ob, Wo_t, 8192, 1024, 2048, 2048, x1, nullptr, nullptr, x, 0);
  ln_bf16<<<8192, 256, 0, stream>>>(x1, ln2_w, ln2_b, h2);

  // FFN in two 2048-wide halves (f-buffer 32 MB instead of 64)
  gemm_nt<<<dim3(16,64), 256, 0, stream>>>(h2, W1_t, 8192, 2048, 1024, 1024, nullptr, fb, b1, nullptr, 2|1);
  gemm_nt<<<dim3(8,64),  256, 0, stream>>>(fb, W2_t, 8192, 1024, 2048, 4096, out, nullptr, b2, x1, 0);
  gemm_nt<<<dim3(16,64), 256, 0, stream>>>(h2, W1_t + (size_t)2048*1024, 8192, 2048, 1024, 1024, nullptr, fb, b1 + 2048, nullptr, 2|1);
  gemm_nt<<<dim3(8,64),  256, 0, stream>>>(fb, W2_t + 2048, 8192, 1024, 2048, 4096, out, nullptr, nullptr, out, 0);
}

// Round 5
// 680.052 us; speedup vs baseline: 1.8438x; 1.0588x over previous
//
#include <hip/hip_runtime.h>
#include <math.h>

typedef short s16;
typedef __attribute__((ext_vector_type(8))) short short8;
typedef __attribute__((ext_vector_type(4))) float f32x4;

__device__ __forceinline__ float bf2f_lo(unsigned u){ return __builtin_bit_cast(float, u << 16); }
__device__ __forceinline__ float bf2f_hi(unsigned u){ return __builtin_bit_cast(float, u & 0xffff0000u); }
__device__ __forceinline__ float bf2f(unsigned short h){ return __builtin_bit_cast(float, (unsigned)h << 16); }
__device__ __forceinline__ s16 f2bf(float f){
  unsigned u = __builtin_bit_cast(unsigned, f);
  u += 0x7fffu + ((u >> 16) & 1u);
  return (s16)(u >> 16);
}
__device__ __forceinline__ void unpack8(int4 v, float* f){
  unsigned a=(unsigned)v.x, b=(unsigned)v.y, c=(unsigned)v.z, d=(unsigned)v.w;
  f[0]=bf2f_lo(a); f[1]=bf2f_hi(a); f[2]=bf2f_lo(b); f[3]=bf2f_hi(b);
  f[4]=bf2f_lo(c); f[5]=bf2f_hi(c); f[6]=bf2f_lo(d); f[7]=bf2f_hi(d);
}
// async global->LDS 16B: lds dest is wave-uniform base + lane*16
__device__ __forceinline__ void gl2lds16(const s16* g, s16* l){
  __builtin_amdgcn_global_load_lds((const __attribute__((address_space(1))) void*)g,
                                   (__attribute__((address_space(3))) void*)l, 16, 0, 0);
}

// ---------------- LayerNorm (fp32 in) -> bf16 out, D=1024, 1 block/row ------
__global__ __launch_bounds__(256) void ln_bf16(const float* __restrict__ x,
                                               const float* __restrict__ w,
                                               const float* __restrict__ b,
                                               s16* __restrict__ out){
  int row = blockIdx.x; int t = threadIdx.x;
  const float* xr = x + (size_t)row * 1024;
  float4 v = *(const float4*)(xr + t*4);
  float s = v.x + v.y + v.z + v.w;
  float ss = v.x*v.x + v.y*v.y + v.z*v.z + v.w*v.w;
  for (int o = 32; o > 0; o >>= 1){ s += __shfl_down(s, o, 64); ss += __shfl_down(ss, o, 64); }
  __shared__ float red[8];
  int wid = t >> 6, lane = t & 63;
  if (lane == 0){ red[wid] = s; red[4+wid] = ss; }
  __syncthreads();
  if (t == 0){
    float S = red[0]+red[1]+red[2]+red[3];
    float SS = red[4]+red[5]+red[6]+red[7];
    red[0] = S * (1.f/1024.f);
    red[1] = SS * (1.f/1024.f);
  }
  __syncthreads();
  float mu = red[0];
  float var = red[1] - mu*mu;
  float rstd = rsqrtf(var + 1e-6f);
  float vv[4] = {v.x, v.y, v.z, v.w};
  short4 o4;
  s16 tmp[4];
  #pragma unroll
  for (int i = 0; i < 4; ++i){
    int c = t*4 + i;
    float val = (vv[i] - mu) * rstd * w[c] + b[c];
    tmp[i] = f2bf(val);
  }
  o4.x = tmp[0]; o4.y = tmp[1]; o4.z = tmp[2]; o4.w = tmp[3];
  *(short4*)(out + (size_t)row*1024 + t*4) = o4;
}

// ---------------- transpose-convert fp32 W[K,N] -> bf16 Wt[N,K], with scale --
__global__ __launch_bounds__(256) void conv_t(const float* __restrict__ W,
                                              s16* __restrict__ Wt,
                                              int K, int N, float scale){
  __shared__ float tile[32][33];
  int n0 = blockIdx.x * 32, k0 = blockIdx.y * 32;
  int tx = threadIdx.x & 31, ty = threadIdx.x >> 5;   // ty 0..7
  #pragma unroll
  for (int i = 0; i < 4; ++i){
    int r = ty + i*8;
    tile[r][tx] = W[(size_t)(k0 + r)*N + n0 + tx];
  }
  __syncthreads();
  #pragma unroll
  for (int i = 0; i < 4; ++i){
    int r = ty + i*8;
    Wt[(size_t)(n0 + r)*K + k0 + tx] = f2bf(tile[tx][r] * scale);
  }
}

// ---------------- bf16 MFMA GEMM 128x128 tile:  C = A[M,K] @ Bt[N,:]^T  ------
// Bt row stride = ldb. flags: bit0 = gelu, bit1 = out bf16
__global__ __launch_bounds__(256,2) void gemm_nt(const s16* __restrict__ A,
                                                 const s16* __restrict__ Bt,
                                                 int M, int N, int K, int ldb,
                                                 float* __restrict__ Cf,
                                                 s16* __restrict__ Cb,
                                                 const float* __restrict__ bias,
                                                 const float* __restrict__ resid,
                                                 int flags){
  __shared__ s16 As[128*32];
  __shared__ s16 Bs[128*32];
  int t = threadIdx.x;
  int m0 = blockIdx.y * 128, n0 = blockIdx.x * 128;
  int w = t >> 6, lane = t & 63;
  int wm = (w >> 1) * 64, wn = (w & 1) * 64;
  int lrow = lane & 15, lq = lane >> 4;
  f32x4 acc[4][4];
  #pragma unroll
  for (int i = 0; i < 4; ++i)
    #pragma unroll
    for (int j = 0; j < 4; ++j) acc[i][j] = (f32x4){0.f,0.f,0.f,0.f};

  const s16* Ag = A  + (size_t)(m0 + (t>>2)) * K   + (t&3)*8;
  const s16* Bg = Bt + (size_t)(n0 + (t>>2)) * ldb + (t&3)*8;
  s16* lA0 = As + w*512;
  s16* lA1 = As + 2048 + w*512;
  s16* lB0 = Bs + w*512;
  s16* lB1 = Bs + 2048 + w*512;

  for (int k0 = 0; k0 < K; k0 += 32){
    __syncthreads();
    gl2lds16(Ag + k0, lA0);
    gl2lds16(Ag + (size_t)64*K + k0, lA1);
    gl2lds16(Bg + k0, lB0);
    gl2lds16(Bg + (size_t)64*ldb + k0, lB1);
    __syncthreads();
    short8 af[4], bfr[4];
    #pragma unroll
    for (int mi = 0; mi < 4; ++mi)
      af[mi] = *(short8*)&As[(wm + mi*16 + lrow)*32 + lq*8];
    #pragma unroll
    for (int ni = 0; ni < 4; ++ni)
      bfr[ni] = *(short8*)&Bs[(wn + ni*16 + lrow)*32 + lq*8];
    #pragma unroll
    for (int mi = 0; mi < 4; ++mi)
      #pragma unroll
      for (int ni = 0; ni < 4; ++ni)
        acc[mi][ni] = __builtin_amdgcn_mfma_f32_16x16x32_bf16(af[mi], bfr[ni], acc[mi][ni], 0, 0, 0);
  }

  bool do_gelu = flags & 1;
  bool out_bf = flags & 2;
  #pragma unroll
  for (int mi = 0; mi < 4; ++mi){
    #pragma unroll
    for (int ni = 0; ni < 4; ++ni){
      int gcol = n0 + wn + ni*16 + lrow;
      float bcol = bias ? bias[gcol] : 0.f;
      int grow_base = m0 + wm + mi*16 + lq*4;
      #pragma unroll
      for (int r = 0; r < 4; ++r){
        int grow = grow_base + r;
        float val = acc[mi][ni][r] + bcol;
        if (do_gelu) val = 0.5f * val * (1.f + erff(val * 0.70710678118654752f));
        if (resid) val += resid[(size_t)grow * N + gcol];
        if (out_bf) Cb[(size_t)grow * N + gcol] = f2bf(val);
        else        Cf[(size_t)grow * N + gcol] = val;
      }
    }
  }
}

// ---------------- bf16 MFMA GEMM 64x128 tile (for small-N GEMMs) -------------
// grid (N/128, M/64). Wave w owns cols [32w,32w+32).
__global__ __launch_bounds__(256,2) void gemm_nt_h(const s16* __restrict__ A,
                                                   const s16* __restrict__ Bt,
                                                   int M, int N, int K, int ldb,
                                                   float* __restrict__ Cf,
                                                   s16* __restrict__ Cb,
                                                   const float* __restrict__ bias,
                                                   const float* __restrict__ resid,
                                                   int flags){
  __shared__ s16 As[64*32];
  __shared__ s16 Bs[128*32];
  int t = threadIdx.x;
  int m0 = blockIdx.y * 64, n0 = blockIdx.x * 128;
  int w = t >> 6, lane = t & 63;
  int lrow = lane & 15, lq = lane >> 4;
  f32x4 acc[4][2];
  #pragma unroll
  for (int i = 0; i < 4; ++i)
    #pragma unroll
    for (int j = 0; j < 2; ++j) acc[i][j] = (f32x4){0.f,0.f,0.f,0.f};

  const s16* Ag = A  + (size_t)(m0 + (t>>2)) * K   + (t&3)*8;
  const s16* Bg = Bt + (size_t)(n0 + (t>>2)) * ldb + (t&3)*8;
  s16* lA  = As + w*512;
  s16* lB0 = Bs + w*512;
  s16* lB1 = Bs + 2048 + w*512;

  for (int k0 = 0; k0 < K; k0 += 32){
    __syncthreads();
    gl2lds16(Ag + k0, lA);
    gl2lds16(Bg + k0, lB0);
    gl2lds16(Bg + (size_t)64*ldb + k0, lB1);
    __syncthreads();
    short8 af[4], bfr[2];
    #pragma unroll
    for (int mi = 0; mi < 4; ++mi)
      af[mi] = *(short8*)&As[(mi*16 + lrow)*32 + lq*8];
    #pragma unroll
    for (int ni = 0; ni < 2; ++ni)
      bfr[ni] = *(short8*)&Bs[(w*32 + ni*16 + lrow)*32 + lq*8];
    #pragma unroll
    for (int mi = 0; mi < 4; ++mi)
      #pragma unroll
      for (int ni = 0; ni < 2; ++ni)
        acc[mi][ni] = __builtin_amdgcn_mfma_f32_16x16x32_bf16(af[mi], bfr[ni], acc[mi][ni], 0, 0, 0);
  }

  bool do_gelu = flags & 1;
  bool out_bf = flags & 2;
  #pragma unroll
  for (int mi = 0; mi < 4; ++mi){
    #pragma unroll
    for (int ni = 0; ni < 2; ++ni){
      int gcol = n0 + w*32 + ni*16 + lrow;
      float bcol = bias ? bias[gcol] : 0.f;
      int grow_base = m0 + mi*16 + lq*4;
      #pragma unroll
      for (int r = 0; r < 4; ++r){
        int grow = grow_base + r;
        float val = acc[mi][ni][r] + bcol;
        if (do_gelu) val = 0.5f * val * (1.f + erff(val * 0.70710678118654752f));
        if (resid) val += resid[(size_t)grow * N + gcol];
        if (out_bf) Cb[(size_t)grow * N + gcol] = f2bf(val);
        else        Cf[(size_t)grow * N + gcol] = val;
      }
    }
  }
}

// ---------------- retention 2a (per batch): U_t[dv][dk] = (d_k*k (x) v)^T ----
// grid 512 = h(8) + n(64); k,v from fused qkv (row stride 4096)
__global__ __launch_bounds__(256,2) void ret_chunksum(const s16* __restrict__ k,
                                                      const s16* __restrict__ v,
                                                      s16* __restrict__ U){
  int bi = blockIdx.x;
  int h = bi & 7, n = bi >> 3;
  int t = threadIdx.x;
  __shared__ s16 ks[128*72];   // ks[dk][s], d_k decay folded
  __shared__ s16 vs[256*72];   // vs[dv][s]
  float log2b = log2f(1.f - exp2f(-5.f - (float)h));
  const s16* kbase = k + (size_t)(n*64)*4096 + h*128;
  const s16* vbase = v + (size_t)(n*64)*4096 + h*256;
  #pragma unroll
  for (int i = 0; i < 4; ++i){
    int e = i*2048 + t*8;
    int s = e >> 7, dk = e & 127;
    int4 kv = *(const int4*)(kbase + (size_t)s*4096 + dk);
    float f[8]; unpack8(kv, f);
    float dec = exp2f(log2b * (float)(63 - s));
    #pragma unroll
    for (int j = 0; j < 8; ++j) ks[(dk+j)*72 + s] = f2bf(f[j]*dec);
  }
  #pragma unroll
  for (int i = 0; i < 8; ++i){
    int e = i*2048 + t*8;
    int s = e >> 8, dv = e & 255;
    int4 vv = *(const int4*)(vbase + (size_t)s*4096 + dv);
    s16 tmp[8]; *(int4*)tmp = vv;
    #pragma unroll
    for (int j = 0; j < 8; ++j) vs[(dv+j)*72 + s] = tmp[j];
  }
  __syncthreads();
  int w = t >> 6, lane = t & 63;
  int m0w = w*64;   // dv rows, 4 tiles per wave
  int lrow = lane & 15, lq = lane >> 4;
  f32x4 acc[4][8];
  #pragma unroll
  for (int mi = 0; mi < 4; ++mi)
    #pragma unroll
    for (int ni = 0; ni < 8; ++ni) acc[mi][ni] = (f32x4){0.f,0.f,0.f,0.f};
  #pragma unroll
  for (int kk = 0; kk < 64; kk += 32){
    short8 af[4], bfr[8];
    #pragma unroll
    for (int mi = 0; mi < 4; ++mi)
      af[mi] = *(short8*)&vs[(m0w + mi*16 + lrow)*72 + kk + lq*8];
    #pragma unroll
    for (int ni = 0; ni < 8; ++ni)
      bfr[ni] = *(short8*)&ks[(ni*16 + lrow)*72 + kk + lq*8];
    #pragma unroll
    for (int mi = 0; mi < 4; ++mi)
      #pragma unroll
      for (int ni = 0; ni < 8; ++ni)
        acc[mi][ni] = __builtin_amdgcn_mfma_f32_16x16x32_bf16(af[mi], bfr[ni], acc[mi][ni], 0, 0, 0);
  }
  s16* Ub = U + ((size_t)(h*64 + n))*32768;
  #pragma unroll
  for (int mi = 0; mi < 4; ++mi)
    #pragma unroll
    for (int ni = 0; ni < 8; ++ni)
      #pragma unroll
      for (int r = 0; r < 4; ++r){
        int row = m0w + mi*16 + lq*4 + r;   // dv
        int col = ni*16 + lrow;             // dk
        Ub[(size_t)row*128 + col] = f2bf(acc[mi][ni][r]);
      }
}

// ---------------- retention 2b (per batch): in-place decay prefix scan -------
__global__ __launch_bounds__(256) void ret_scan(s16* __restrict__ US){
  int tid = blockIdx.x*256 + threadIdx.x;       // 32768 threads
  int h = tid >> 12;
  int rem = tid & 4095;
  int dv = rem >> 4, dk0 = (rem & 15)*8;
  float log2b = log2f(1.f - exp2f(-5.f - (float)h));
  float dc = exp2f(log2b * 64.f);
  s16* base = US + (size_t)h*64*32768 + (size_t)dv*128 + dk0;
  float acc[8] = {0.f,0.f,0.f,0.f,0.f,0.f,0.f,0.f};
  #pragma unroll 4
  for (int n = 0; n < 64; ++n){
    s16* p = base + (size_t)n*32768;
    int4 u4 = *(const int4*)p;
    float uf[8]; unpack8(u4, uf);
    s16 sb[8];
    #pragma unroll
    for (int j = 0; j < 8; ++j) sb[j] = f2bf(acc[j]);
    *(int4*)p = *(int4*)sb;
    #pragma unroll
    for (int j = 0; j < 8; ++j) acc[j] = acc[j]*dc + uf[j];
  }
}

// ---------------- retention fused (per batch): O = mask(qk^T)@v + dq*(q@S) ---
// grid 512 = h(8) + n(64). q,k,v from fused qkv (stride 4096); S_t [h][n][256][128]
__global__ __launch_bounds__(256,2) void ret_attn(const s16* __restrict__ q,
                                                  const s16* __restrict__ k,
                                                  const s16* __restrict__ v,
                                                  const s16* __restrict__ S,
                                                  s16* __restrict__ o){
  int bi = blockIdx.x;
  int h = bi & 7, n = bi >> 3;
  int t = threadIdx.x;
  int w = t >> 6, lane = t & 63;
  int lrow = lane & 15, lq = lane >> 4;
  float log2b = log2f(1.f - exp2f(-5.f - (float)h));
  __shared__ s16 As[64*72];    // masked scores, A-operand staging
  __shared__ s16 vs[256*72];   // v^T [dv][s]

  // stage v transposed
  const s16* vbase = v + (size_t)(n*64)*4096 + h*256;
  #pragma unroll
  for (int i = 0; i < 8; ++i){
    int e = i*2048 + t*8;
    int s = e >> 8, dv = e & 255;
    int4 vv = *(const int4*)(vbase + (size_t)s*4096 + dv);
    s16 tmp[8]; *(int4*)tmp = vv;
    #pragma unroll
    for (int j = 0; j < 8; ++j) vs[(dv+j)*72 + s] = tmp[j];
  }

  // phase 1: wave w computes A[:, 16w:16w+16] = q @ k^T, masked
  const s16* qbase = q + (size_t)(n*64)*4096 + h*128;
  const s16* kbase = k + (size_t)(n*64)*4096 + h*128;
  short8 qf[4][4];   // [row-tile][kstep], reused in phase 2
  #pragma unroll
  for (int ti = 0; ti < 4; ++ti)
    #pragma unroll
    for (int c = 0; c < 4; ++c)
      qf[ti][c] = *(const short8*)(qbase + (size_t)(ti*16 + lrow)*4096 + c*32 + lq*8);
  short8 kf[4];
  #pragma unroll
  for (int c = 0; c < 4; ++c)
    kf[c] = *(const short8*)(kbase + (size_t)(16*w + lrow)*4096 + c*32 + lq*8);
  #pragma unroll
  for (int ti = 0; ti < 4; ++ti){
    f32x4 acc_a = (f32x4){0.f,0.f,0.f,0.f};
    #pragma unroll
    for (int c = 0; c < 4; ++c)
      acc_a = __builtin_amdgcn_mfma_f32_16x16x32_bf16(qf[ti][c], kf[c], acc_a, 0, 0, 0);
    #pragma unroll
    for (int r = 0; r < 4; ++r){
      int ti_idx = ti*16 + lq*4 + r;
      int s_idx = 16*w + lrow;
      int d = ti_idx - s_idx;
      float val = (d >= 0) ? acc_a[r] * exp2f(log2b * (float)d) : 0.f;
      As[ti_idx*72 + s_idx] = f2bf(val);
    }
  }
  __syncthreads();

  // phase 2: wave w owns dv cols [64w, 64w+64)
  f32x4 acc[4][4];
  #pragma unroll
  for (int mi = 0; mi < 4; ++mi)
    #pragma unroll
    for (int nj = 0; nj < 4; ++nj) acc[mi][nj] = (f32x4){0.f,0.f,0.f,0.f};

  // q @ S  (K = 128)
  const s16* Sbase = S + ((size_t)(h*64 + n)*256 + w*64)*128;
  #pragma unroll
  for (int c = 0; c < 4; ++c){
    short8 bf[4];
    #pragma unroll
    for (int nj = 0; nj < 4; ++nj)
      bf[nj] = *(const short8*)(Sbase + (size_t)(nj*16 + lrow)*128 + c*32 + lq*8);
    #pragma unroll
    for (int mi = 0; mi < 4; ++mi)
      #pragma unroll
      for (int nj = 0; nj < 4; ++nj)
        acc[mi][nj] = __builtin_amdgcn_mfma_f32_16x16x32_bf16(qf[mi][c], bf[nj], acc[mi][nj], 0, 0, 0);
  }
  // scale by d_q = b^(row+1)
  #pragma unroll
  for (int mi = 0; mi < 4; ++mi){
    #pragma unroll
    for (int r = 0; r < 4; ++r){
      float dq = exp2f(log2b * (float)(mi*16 + lq*4 + r + 1));
      #pragma unroll
      for (int nj = 0; nj < 4; ++nj) acc[mi][nj][r] *= dq;
    }
  }
  // A @ v  (K = 64)
  #pragma unroll
  for (int c = 0; c < 2; ++c){
    short8 af[4], bf[4];
    #pragma unroll
    for (int mi = 0; mi < 4; ++mi)
      af[mi] = *(short8*)&As[(mi*16 + lrow)*72 + c*32 + lq*8];
    #pragma unroll
    for (int nj = 0; nj < 4; ++nj)
      bf[nj] = *(short8*)&vs[(w*64 + nj*16 + lrow)*72 + c*32 + lq*8];
    #pragma unroll
    for (int mi = 0; mi < 4; ++mi)
      #pragma unroll
      for (int nj = 0; nj < 4; ++nj)
        acc[mi][nj] = __builtin_amdgcn_mfma_f32_16x16x32_bf16(af[mi], bf[nj], acc[mi][nj], 0, 0, 0);
  }
  // write O
  s16* obase = o + (size_t)(n*64)*2048 + h*256;
  #pragma unroll
  for (int mi = 0; mi < 4; ++mi)
    #pragma unroll
    for (int nj = 0; nj < 4; ++nj)
      #pragma unroll
      for (int r = 0; r < 4; ++r){
        int row = mi*16 + lq*4 + r;
        int col = w*64 + nj*16 + lrow;
        obase[(size_t)row*2048 + col] = f2bf(acc[mi][nj][r]);
      }
}

extern "C" void kernel_launch(void* const* d_in, const int* in_sizes, int n_in,
                              void* d_out, int out_size, void* d_ws, size_t ws_size,
                              hipStream_t stream) {
  (void)in_sizes; (void)n_in; (void)out_size; (void)ws_size;
  const float* x     = (const float*)d_in[0];
  const float* ln1_w = (const float*)d_in[1];
  const float* ln1_b = (const float*)d_in[2];
  const float* Wq    = (const float*)d_in[3];
  const float* Wk    = (const float*)d_in[4];
  const float* Wv    = (const float*)d_in[5];
  const float* Wo    = (const float*)d_in[6];
  const float* ln2_w = (const float*)d_in[7];
  const float* ln2_b = (const float*)d_in[8];
  const float* W1    = (const float*)d_in[9];
  const float* b1    = (const float*)d_in[10];
  const float* W2    = (const float*)d_in[11];
  const float* b2    = (const float*)d_in[12];
  float* out = (float*)d_out;
  char* ws = (char*)d_ws;

  // ---- static arena, peak 172 MB (lifetime-aliased) ----
  const size_t MB = 1ull << 20;
  s16* Wqkv_t = (s16*)(ws + 0*MB);   // [0,8)  rows: 0-1023 q, 1024-2047 k, 2048-4095 v
  s16* Wo_t = (s16*)(ws + 8*MB);     // [8,12)
  s16* W1_t = (s16*)(ws + 12*MB);    // [12,20)
  s16* W2_t = (s16*)(ws + 20*MB);    // [20,28)
  s16* hbuf = (s16*)(ws + 28*MB);    // [28,44)  dead after QKV gemm
  s16* h2   = (s16*)(ws + 28*MB);    // [28,44)  alias dead hbuf (post-retention)
  s16* qkv  = (s16*)(ws + 44*MB);    // [44,108) [8192,4096] bf16, dead after ret_attn(b1)
  float* x1 = (float*)(ws + 44*MB);  // [44,76)  alias dead qkv head (post-retention)
  s16* fb   = (s16*)(ws + 76*MB);    // [76,140) alias dead qkv tail + US (FFN acts)
  s16* US   = (s16*)(ws + 108*MB);   // [108,140) bf16 per-batch U->S (in-place scan)
  s16* ob   = (s16*)(ws + 140*MB);   // [140,172)

  // weight transpose-convert (DK^-0.5 folded into Wq)
  conv_t<<<dim3(32,32),  256, 0, stream>>>(Wq, Wqkv_t, 1024, 1024, 0.08838834764831845f);
  conv_t<<<dim3(32,32),  256, 0, stream>>>(Wk, Wqkv_t + (size_t)1024*1024, 1024, 1024, 1.f);
  conv_t<<<dim3(64,32),  256, 0, stream>>>(Wv, Wqkv_t + (size_t)2048*1024, 1024, 2048, 1.f);
  conv_t<<<dim3(32,64),  256, 0, stream>>>(Wo, Wo_t, 2048, 1024, 1.f);
  conv_t<<<dim3(128,32), 256, 0, stream>>>(W1, W1_t, 1024, 4096, 1.f);
  conv_t<<<dim3(32,128), 256, 0, stream>>>(W2, W2_t, 4096, 1024, 1.f);

  ln_bf16<<<8192, 256, 0, stream>>>(x, ln1_w, ln1_b, hbuf);

  // fused QKV: [8192,4096] = hbuf @ Wqkv^T, grid 2048 blocks
  gemm_nt<<<dim3(32,64), 256, 0, stream>>>(hbuf, Wqkv_t, 8192, 4096, 1024, 1024, nullptr, qkv, nullptr, nullptr, 2);

  for (int b = 0; b < 2; ++b){
    const s16* q_b = qkv + (size_t)b*4096*4096;
    const s16* k_b = q_b + 1024;
    const s16* v_b = q_b + 2048;
    s16* ob_b = ob + (size_t)b*4096*2048;
    ret_chunksum<<<512, 256, 0, stream>>>(k_b, v_b, US);
    ret_scan<<<128, 256, 0, stream>>>(US);
    ret_attn<<<512, 256, 0, stream>>>(q_b, k_b, v_b, US, ob_b);
  }

  // Wo: x1 = x + ob @ Wo^T   (64x128 tile, grid 1024 blocks)
  gemm_nt_h<<<dim3(8,128), 256, 0, stream>>>(ob, Wo_t, 8192, 1024, 2048, 2048, x1, nullptr, nullptr, x, 0);
  ln_bf16<<<8192, 256, 0, stream>>>(x1, ln2_w, ln2_b, h2);

  // FFN: fb = gelu(h2 @ W1^T + b1)  [8192,4096], grid 2048 blocks
  gemm_nt<<<dim3(32,64), 256, 0, stream>>>(h2, W1_t, 8192, 4096, 1024, 1024, nullptr, fb, b1, nullptr, 2|1);
  // out = x1 + b2 + fb @ W2^T   (64x128 tile, grid 1024 blocks, K=4096)
  gemm_nt_h<<<dim3(8,128), 256, 0, stream>>>(fb, W2_t, 8192, 1024, 4096, 4096, out, nullptr, b2, x1, 0);
}

// Round 6
// 660.835 us; speedup vs baseline: 1.8974x; 1.0291x over previous
//
#include <hip/hip_runtime.h>
#include <math.h>

typedef short s16;
typedef __attribute__((ext_vector_type(8))) short short8;
typedef __attribute__((ext_vector_type(4))) float f32x4;

__device__ __forceinline__ float bf2f_lo(unsigned u){ return __builtin_bit_cast(float, u << 16); }
__device__ __forceinline__ float bf2f_hi(unsigned u){ return __builtin_bit_cast(float, u & 0xffff0000u); }
__device__ __forceinline__ float bf2f(unsigned short h){ return __builtin_bit_cast(float, (unsigned)h << 16); }
__device__ __forceinline__ s16 f2bf(float f){
  unsigned u = __builtin_bit_cast(unsigned, f);
  u += 0x7fffu + ((u >> 16) & 1u);
  return (s16)(u >> 16);
}
__device__ __forceinline__ void unpack8(int4 v, float* f){
  unsigned a=(unsigned)v.x, b=(unsigned)v.y, c=(unsigned)v.z, d=(unsigned)v.w;
  f[0]=bf2f_lo(a); f[1]=bf2f_hi(a); f[2]=bf2f_lo(b); f[3]=bf2f_hi(b);
  f[4]=bf2f_lo(c); f[5]=bf2f_hi(c); f[6]=bf2f_lo(d); f[7]=bf2f_hi(d);
}
// async global->LDS 16B: lds dest is wave-uniform base + lane*16
__device__ __forceinline__ void gl2lds16(const s16* g, s16* l){
  __builtin_amdgcn_global_load_lds((const __attribute__((address_space(1))) void*)g,
                                   (__attribute__((address_space(3))) void*)l, 16, 0, 0);
}

// ---------------- LayerNorm (fp32 in) -> bf16 out, D=1024, 1 block/row ------
__global__ __launch_bounds__(256) void ln_bf16(const float* __restrict__ x,
                                               const float* __restrict__ w,
                                               const float* __restrict__ b,
                                               s16* __restrict__ out){
  int row = blockIdx.x; int t = threadIdx.x;
  const float* xr = x + (size_t)row * 1024;
  float4 v = *(const float4*)(xr + t*4);
  float s = v.x + v.y + v.z + v.w;
  float ss = v.x*v.x + v.y*v.y + v.z*v.z + v.w*v.w;
  for (int o = 32; o > 0; o >>= 1){ s += __shfl_down(s, o, 64); ss += __shfl_down(ss, o, 64); }
  __shared__ float red[8];
  int wid = t >> 6, lane = t & 63;
  if (lane == 0){ red[wid] = s; red[4+wid] = ss; }
  __syncthreads();
  if (t == 0){
    float S = red[0]+red[1]+red[2]+red[3];
    float SS = red[4]+red[5]+red[6]+red[7];
    red[0] = S * (1.f/1024.f);
    red[1] = SS * (1.f/1024.f);
  }
  __syncthreads();
  float mu = red[0];
  float var = red[1] - mu*mu;
  float rstd = rsqrtf(var + 1e-6f);
  float vv[4] = {v.x, v.y, v.z, v.w};
  short4 o4;
  s16 tmp[4];
  #pragma unroll
  for (int i = 0; i < 4; ++i){
    int c = t*4 + i;
    float val = (vv[i] - mu) * rstd * w[c] + b[c];
    tmp[i] = f2bf(val);
  }
  o4.x = tmp[0]; o4.y = tmp[1]; o4.z = tmp[2]; o4.w = tmp[3];
  *(short4*)(out + (size_t)row*1024 + t*4) = o4;
}

// ---------------- transpose-convert fp32 W[K,N] -> bf16 Wt[N,K], with scale --
__global__ __launch_bounds__(256) void conv_t(const float* __restrict__ W,
                                              s16* __restrict__ Wt,
                                              int K, int N, float scale){
  __shared__ float tile[32][33];
  int n0 = blockIdx.x * 32, k0 = blockIdx.y * 32;
  int tx = threadIdx.x & 31, ty = threadIdx.x >> 5;   // ty 0..7
  #pragma unroll
  for (int i = 0; i < 4; ++i){
    int r = ty + i*8;
    tile[r][tx] = W[(size_t)(k0 + r)*N + n0 + tx];
  }
  __syncthreads();
  #pragma unroll
  for (int i = 0; i < 4; ++i){
    int r = ty + i*8;
    Wt[(size_t)(n0 + r)*K + k0 + tx] = f2bf(tile[tx][r] * scale);
  }
}

// XCD swizzle: 1D grid, tiles_y M-tiles (divisible by 8). Each XCD owns a
// disjoint M-row stripe (A fetched once, per-XCD L2); N iterated slowly so
// the B-slab stays hot across sy consecutive on-XCD blocks.
__device__ __forceinline__ void xcd_tile(int tiles_y, int& tx, int& ty){
  int id = blockIdx.x;
  int sy = tiles_y >> 3;
  int xcd = id & 7, p = id >> 3;
  ty = xcd * sy + (p % sy);
  tx = p / sy;
}

// ---------------- bf16 MFMA GEMM 128x128 tile:  C = A[M,K] @ Bt[N,:]^T  ------
// 1D grid = (N/128)*(M/128); tiles_y = M/128. flags: bit0 gelu, bit1 out bf16
__global__ __launch_bounds__(256,2) void gemm_nt(const s16* __restrict__ A,
                                                 const s16* __restrict__ Bt,
                                                 int M, int N, int K, int ldb,
                                                 float* __restrict__ Cf,
                                                 s16* __restrict__ Cb,
                                                 const float* __restrict__ bias,
                                                 const float* __restrict__ resid,
                                                 int flags, int tiles_y){
  __shared__ s16 As[128*32];
  __shared__ s16 Bs[128*32];
  int t = threadIdx.x;
  int tx, ty; xcd_tile(tiles_y, tx, ty);
  int m0 = ty * 128, n0 = tx * 128;
  int w = t >> 6, lane = t & 63;
  int wm = (w >> 1) * 64, wn = (w & 1) * 64;
  int lrow = lane & 15, lq = lane >> 4;
  f32x4 acc[4][4];
  #pragma unroll
  for (int i = 0; i < 4; ++i)
    #pragma unroll
    for (int j = 0; j < 4; ++j) acc[i][j] = (f32x4){0.f,0.f,0.f,0.f};

  const s16* Ag = A  + (size_t)(m0 + (t>>2)) * K   + (t&3)*8;
  const s16* Bg = Bt + (size_t)(n0 + (t>>2)) * ldb + (t&3)*8;
  s16* lA0 = As + w*512;
  s16* lA1 = As + 2048 + w*512;
  s16* lB0 = Bs + w*512;
  s16* lB1 = Bs + 2048 + w*512;

  for (int k0 = 0; k0 < K; k0 += 32){
    __syncthreads();
    gl2lds16(Ag + k0, lA0);
    gl2lds16(Ag + (size_t)64*K + k0, lA1);
    gl2lds16(Bg + k0, lB0);
    gl2lds16(Bg + (size_t)64*ldb + k0, lB1);
    __syncthreads();
    short8 af[4], bfr[4];
    #pragma unroll
    for (int mi = 0; mi < 4; ++mi)
      af[mi] = *(short8*)&As[(wm + mi*16 + lrow)*32 + lq*8];
    #pragma unroll
    for (int ni = 0; ni < 4; ++ni)
      bfr[ni] = *(short8*)&Bs[(wn + ni*16 + lrow)*32 + lq*8];
    #pragma unroll
    for (int mi = 0; mi < 4; ++mi)
      #pragma unroll
      for (int ni = 0; ni < 4; ++ni)
        acc[mi][ni] = __builtin_amdgcn_mfma_f32_16x16x32_bf16(af[mi], bfr[ni], acc[mi][ni], 0, 0, 0);
  }

  bool do_gelu = flags & 1;
  bool out_bf = flags & 2;
  #pragma unroll
  for (int mi = 0; mi < 4; ++mi){
    #pragma unroll
    for (int ni = 0; ni < 4; ++ni){
      int gcol = n0 + wn + ni*16 + lrow;
      float bcol = bias ? bias[gcol] : 0.f;
      int grow_base = m0 + wm + mi*16 + lq*4;
      #pragma unroll
      for (int r = 0; r < 4; ++r){
        int grow = grow_base + r;
        float val = acc[mi][ni][r] + bcol;
        if (do_gelu) val = 0.5f * val * (1.f + erff(val * 0.70710678118654752f));
        if (resid) val += resid[(size_t)grow * N + gcol];
        if (out_bf) Cb[(size_t)grow * N + gcol] = f2bf(val);
        else        Cf[(size_t)grow * N + gcol] = val;
      }
    }
  }
}

// ---------------- bf16 MFMA GEMM 64x128 tile (small-N GEMMs) -----------------
// 1D grid = (N/128)*(M/64); tiles_y = M/64. Wave w owns cols [32w,32w+32).
__global__ __launch_bounds__(256,2) void gemm_nt_h(const s16* __restrict__ A,
                                                   const s16* __restrict__ Bt,
                                                   int M, int N, int K, int ldb,
                                                   float* __restrict__ Cf,
                                                   s16* __restrict__ Cb,
                                                   const float* __restrict__ bias,
                                                   const float* __restrict__ resid,
                                                   int flags, int tiles_y){
  __shared__ s16 As[64*32];
  __shared__ s16 Bs[128*32];
  int t = threadIdx.x;
  int tx, ty; xcd_tile(tiles_y, tx, ty);
  int m0 = ty * 64, n0 = tx * 128;
  int w = t >> 6, lane = t & 63;
  int lrow = lane & 15, lq = lane >> 4;
  f32x4 acc[4][2];
  #pragma unroll
  for (int i = 0; i < 4; ++i)
    #pragma unroll
    for (int j = 0; j < 2; ++j) acc[i][j] = (f32x4){0.f,0.f,0.f,0.f};

  const s16* Ag = A  + (size_t)(m0 + (t>>2)) * K   + (t&3)*8;
  const s16* Bg = Bt + (size_t)(n0 + (t>>2)) * ldb + (t&3)*8;
  s16* lA  = As + w*512;
  s16* lB0 = Bs + w*512;
  s16* lB1 = Bs + 2048 + w*512;

  for (int k0 = 0; k0 < K; k0 += 32){
    __syncthreads();
    gl2lds16(Ag + k0, lA);
    gl2lds16(Bg + k0, lB0);
    gl2lds16(Bg + (size_t)64*ldb + k0, lB1);
    __syncthreads();
    short8 af[4], bfr[2];
    #pragma unroll
    for (int mi = 0; mi < 4; ++mi)
      af[mi] = *(short8*)&As[(mi*16 + lrow)*32 + lq*8];
    #pragma unroll
    for (int ni = 0; ni < 2; ++ni)
      bfr[ni] = *(short8*)&Bs[(w*32 + ni*16 + lrow)*32 + lq*8];
    #pragma unroll
    for (int mi = 0; mi < 4; ++mi)
      #pragma unroll
      for (int ni = 0; ni < 2; ++ni)
        acc[mi][ni] = __builtin_amdgcn_mfma_f32_16x16x32_bf16(af[mi], bfr[ni], acc[mi][ni], 0, 0, 0);
  }

  bool do_gelu = flags & 1;
  bool out_bf = flags & 2;
  #pragma unroll
  for (int mi = 0; mi < 4; ++mi){
    #pragma unroll
    for (int ni = 0; ni < 2; ++ni){
      int gcol = n0 + w*32 + ni*16 + lrow;
      float bcol = bias ? bias[gcol] : 0.f;
      int grow_base = m0 + mi*16 + lq*4;
      #pragma unroll
      for (int r = 0; r < 4; ++r){
        int grow = grow_base + r;
        float val = acc[mi][ni][r] + bcol;
        if (do_gelu) val = 0.5f * val * (1.f + erff(val * 0.70710678118654752f));
        if (resid) val += resid[(size_t)grow * N + gcol];
        if (out_bf) Cb[(size_t)grow * N + gcol] = f2bf(val);
        else        Cf[(size_t)grow * N + gcol] = val;
      }
    }
  }
}

// ---------------- retention 2a (per batch): U_t[dv][dk] = (d_k*k (x) v)^T ----
// grid 512 = h(8) + n(64); k,v from fused qkv (row stride 4096)
__global__ __launch_bounds__(256,2) void ret_chunksum(const s16* __restrict__ k,
                                                      const s16* __restrict__ v,
                                                      s16* __restrict__ U){
  int bi = blockIdx.x;
  int h = bi & 7, n = bi >> 3;
  int t = threadIdx.x;
  __shared__ s16 ks[128*72];   // ks[dk][s], d_k decay folded
  __shared__ s16 vs[256*72];   // vs[dv][s]
  float log2b = log2f(1.f - exp2f(-5.f - (float)h));
  const s16* kbase = k + (size_t)(n*64)*4096 + h*128;
  const s16* vbase = v + (size_t)(n*64)*4096 + h*256;
  #pragma unroll
  for (int i = 0; i < 4; ++i){
    int e = i*2048 + t*8;
    int s = e >> 7, dk = e & 127;
    int4 kv = *(const int4*)(kbase + (size_t)s*4096 + dk);
    float f[8]; unpack8(kv, f);
    float dec = exp2f(log2b * (float)(63 - s));
    #pragma unroll
    for (int j = 0; j < 8; ++j) ks[(dk+j)*72 + s] = f2bf(f[j]*dec);
  }
  #pragma unroll
  for (int i = 0; i < 8; ++i){
    int e = i*2048 + t*8;
    int s = e >> 8, dv = e & 255;
    int4 vv = *(const int4*)(vbase + (size_t)s*4096 + dv);
    s16 tmp[8]; *(int4*)tmp = vv;
    #pragma unroll
    for (int j = 0; j < 8; ++j) vs[(dv+j)*72 + s] = tmp[j];
  }
  __syncthreads();
  int w = t >> 6, lane = t & 63;
  int m0w = w*64;   // dv rows, 4 tiles per wave
  int lrow = lane & 15, lq = lane >> 4;
  f32x4 acc[4][8];
  #pragma unroll
  for (int mi = 0; mi < 4; ++mi)
    #pragma unroll
    for (int ni = 0; ni < 8; ++ni) acc[mi][ni] = (f32x4){0.f,0.f,0.f,0.f};
  #pragma unroll
  for (int kk = 0; kk < 64; kk += 32){
    short8 af[4], bfr[8];
    #pragma unroll
    for (int mi = 0; mi < 4; ++mi)
      af[mi] = *(short8*)&vs[(m0w + mi*16 + lrow)*72 + kk + lq*8];
    #pragma unroll
    for (int ni = 0; ni < 8; ++ni)
      bfr[ni] = *(short8*)&ks[(ni*16 + lrow)*72 + kk + lq*8];
    #pragma unroll
    for (int mi = 0; mi < 4; ++mi)
      #pragma unroll
      for (int ni = 0; ni < 8; ++ni)
        acc[mi][ni] = __builtin_amdgcn_mfma_f32_16x16x32_bf16(af[mi], bfr[ni], acc[mi][ni], 0, 0, 0);
  }
  s16* Ub = U + ((size_t)(h*64 + n))*32768;
  #pragma unroll
  for (int mi = 0; mi < 4; ++mi)
    #pragma unroll
    for (int ni = 0; ni < 8; ++ni)
      #pragma unroll
      for (int r = 0; r < 4; ++r){
        int row = m0w + mi*16 + lq*4 + r;   // dv
        int col = ni*16 + lrow;             // dk
        Ub[(size_t)row*128 + col] = f2bf(acc[mi][ni][r]);
      }
}

// ---------------- retention 2b (per batch): in-place decay prefix scan -------
__global__ __launch_bounds__(256) void ret_scan(s16* __restrict__ US){
  int tid = blockIdx.x*256 + threadIdx.x;       // 32768 threads
  int h = tid >> 12;
  int rem = tid & 4095;
  int dv = rem >> 4, dk0 = (rem & 15)*8;
  float log2b = log2f(1.f - exp2f(-5.f - (float)h));
  float dc = exp2f(log2b * 64.f);
  s16* base = US + (size_t)h*64*32768 + (size_t)dv*128 + dk0;
  float acc[8] = {0.f,0.f,0.f,0.f,0.f,0.f,0.f,0.f};
  #pragma unroll 4
  for (int n = 0; n < 64; ++n){
    s16* p = base + (size_t)n*32768;
    int4 u4 = *(const int4*)p;
    float uf[8]; unpack8(u4, uf);
    s16 sb[8];
    #pragma unroll
    for (int j = 0; j < 8; ++j) sb[j] = f2bf(acc[j]);
    *(int4*)p = *(int4*)sb;
    #pragma unroll
    for (int j = 0; j < 8; ++j) acc[j] = acc[j]*dc + uf[j];
  }
}

// ---------------- retention fused (per batch): O = mask(qk^T)@v + dq*(q@S) ---
// grid 512 = h(8) + n(64). q,k,v from fused qkv (stride 4096); S_t [h][n][256][128]
__global__ __launch_bounds__(256,2) void ret_attn(const s16* __restrict__ q,
                                                  const s16* __restrict__ k,
                                                  const s16* __restrict__ v,
                                                  const s16* __restrict__ S,
                                                  s16* __restrict__ o){
  int bi = blockIdx.x;
  int h = bi & 7, n = bi >> 3;
  int t = threadIdx.x;
  int w = t >> 6, lane = t & 63;
  int lrow = lane & 15, lq = lane >> 4;
  float log2b = log2f(1.f - exp2f(-5.f - (float)h));
  __shared__ s16 As[64*72];    // masked scores, A-operand staging
  __shared__ s16 vs[256*72];   // v^T [dv][s]

  // stage v transposed
  const s16* vbase = v + (size_t)(n*64)*4096 + h*256;
  #pragma unroll
  for (int i = 0; i < 8; ++i){
    int e = i*2048 + t*8;
    int s = e >> 8, dv = e & 255;
    int4 vv = *(const int4*)(vbase + (size_t)s*4096 + dv);
    s16 tmp[8]; *(int4*)tmp = vv;
    #pragma unroll
    for (int j = 0; j < 8; ++j) vs[(dv+j)*72 + s] = tmp[j];
  }

  // phase 1: wave w computes A[:, 16w:16w+16] = q @ k^T, masked
  const s16* qbase = q + (size_t)(n*64)*4096 + h*128;
  const s16* kbase = k + (size_t)(n*64)*4096 + h*128;
  short8 qf[4][4];   // [row-tile][kstep], reused in phase 2
  #pragma unroll
  for (int ti = 0; ti < 4; ++ti)
    #pragma unroll
    for (int c = 0; c < 4; ++c)
      qf[ti][c] = *(const short8*)(qbase + (size_t)(ti*16 + lrow)*4096 + c*32 + lq*8);
  short8 kf[4];
  #pragma unroll
  for (int c = 0; c < 4; ++c)
    kf[c] = *(const short8*)(kbase + (size_t)(16*w + lrow)*4096 + c*32 + lq*8);
  #pragma unroll
  for (int ti = 0; ti < 4; ++ti){
    f32x4 acc_a = (f32x4){0.f,0.f,0.f,0.f};
    #pragma unroll
    for (int c = 0; c < 4; ++c)
      acc_a = __builtin_amdgcn_mfma_f32_16x16x32_bf16(qf[ti][c], kf[c], acc_a, 0, 0, 0);
    #pragma unroll
    for (int r = 0; r < 4; ++r){
      int ti_idx = ti*16 + lq*4 + r;
      int s_idx = 16*w + lrow;
      int d = ti_idx - s_idx;
      float val = (d >= 0) ? acc_a[r] * exp2f(log2b * (float)d) : 0.f;
      As[ti_idx*72 + s_idx] = f2bf(val);
    }
  }
  __syncthreads();

  // phase 2: wave w owns dv cols [64w, 64w+64)
  f32x4 acc[4][4];
  #pragma unroll
  for (int mi = 0; mi < 4; ++mi)
    #pragma unroll
    for (int nj = 0; nj < 4; ++nj) acc[mi][nj] = (f32x4){0.f,0.f,0.f,0.f};

  // q @ S  (K = 128)
  const s16* Sbase = S + ((size_t)(h*64 + n)*256 + w*64)*128;
  #pragma unroll
  for (int c = 0; c < 4; ++c){
    short8 bf[4];
    #pragma unroll
    for (int nj = 0; nj < 4; ++nj)
      bf[nj] = *(const short8*)(Sbase + (size_t)(nj*16 + lrow)*128 + c*32 + lq*8);
    #pragma unroll
    for (int mi = 0; mi < 4; ++mi)
      #pragma unroll
      for (int nj = 0; nj < 4; ++nj)
        acc[mi][nj] = __builtin_amdgcn_mfma_f32_16x16x32_bf16(qf[mi][c], bf[nj], acc[mi][nj], 0, 0, 0);
  }
  // scale by d_q = b^(row+1)
  #pragma unroll
  for (int mi = 0; mi < 4; ++mi){
    #pragma unroll
    for (int r = 0; r < 4; ++r){
      float dq = exp2f(log2b * (float)(mi*16 + lq*4 + r + 1));
      #pragma unroll
      for (int nj = 0; nj < 4; ++nj) acc[mi][nj][r] *= dq;
    }
  }
  // A @ v  (K = 64)
  #pragma unroll
  for (int c = 0; c < 2; ++c){
    short8 af[4], bf[4];
    #pragma unroll
    for (int mi = 0; mi < 4; ++mi)
      af[mi] = *(short8*)&As[(mi*16 + lrow)*72 + c*32 + lq*8];
    #pragma unroll
    for (int nj = 0; nj < 4; ++nj)
      bf[nj] = *(short8*)&vs[(w*64 + nj*16 + lrow)*72 + c*32 + lq*8];
    #pragma unroll
    for (int mi = 0; mi < 4; ++mi)
      #pragma unroll
      for (int nj = 0; nj < 4; ++nj)
        acc[mi][nj] = __builtin_amdgcn_mfma_f32_16x16x32_bf16(af[mi], bf[nj], acc[mi][nj], 0, 0, 0);
  }
  // write O
  s16* obase = o + (size_t)(n*64)*2048 + h*256;
  #pragma unroll
  for (int mi = 0; mi < 4; ++mi)
    #pragma unroll
    for (int nj = 0; nj < 4; ++nj)
      #pragma unroll
      for (int r = 0; r < 4; ++r){
        int row = mi*16 + lq*4 + r;
        int col = w*64 + nj*16 + lrow;
        obase[(size_t)row*2048 + col] = f2bf(acc[mi][nj][r]);
      }
}

extern "C" void kernel_launch(void* const* d_in, const int* in_sizes, int n_in,
                              void* d_out, int out_size, void* d_ws, size_t ws_size,
                              hipStream_t stream) {
  (void)in_sizes; (void)n_in; (void)out_size; (void)ws_size;
  const float* x     = (const float*)d_in[0];
  const float* ln1_w = (const float*)d_in[1];
  const float* ln1_b = (const float*)d_in[2];
  const float* Wq    = (const float*)d_in[3];
  const float* Wk    = (const float*)d_in[4];
  const float* Wv    = (const float*)d_in[5];
  const float* Wo    = (const float*)d_in[6];
  const float* ln2_w = (const float*)d_in[7];
  const float* ln2_b = (const float*)d_in[8];
  const float* W1    = (const float*)d_in[9];
  const float* b1    = (const float*)d_in[10];
  const float* W2    = (const float*)d_in[11];
  const float* b2    = (const float*)d_in[12];
  float* out = (float*)d_out;
  char* ws = (char*)d_ws;

  // ---- static arena, peak 172 MB (lifetime-aliased) ----
  const size_t MB = 1ull << 20;
  s16* Wqkv_t = (s16*)(ws + 0*MB);   // [0,8)  rows: 0-1023 q, 1024-2047 k, 2048-4095 v
  s16* Wo_t = (s16*)(ws + 8*MB);     // [8,12)
  s16* W1_t = (s16*)(ws + 12*MB);    // [12,20)
  s16* W2_t = (s16*)(ws + 20*MB);    // [20,28)
  s16* hbuf = (s16*)(ws + 28*MB);    // [28,44)  dead after QKV gemm
  s16* h2   = (s16*)(ws + 28*MB);    // [28,44)  alias dead hbuf (post-retention)
  s16* qkv  = (s16*)(ws + 44*MB);    // [44,108) [8192,4096] bf16, dead after ret_attn(b1)
  float* x1 = (float*)(ws + 44*MB);  // [44,76)  alias dead qkv head (post-retention)
  s16* fb   = (s16*)(ws + 76*MB);    // [76,140) alias dead qkv tail + US (FFN acts)
  s16* US   = (s16*)(ws + 108*MB);   // [108,140) bf16 per-batch U->S (in-place scan)
  s16* ob   = (s16*)(ws + 140*MB);   // [140,172)

  // weight transpose-convert (DK^-0.5 folded into Wq)
  conv_t<<<dim3(32,32),  256, 0, stream>>>(Wq, Wqkv_t, 1024, 1024, 0.08838834764831845f);
  conv_t<<<dim3(32,32),  256, 0, stream>>>(Wk, Wqkv_t + (size_t)1024*1024, 1024, 1024, 1.f);
  conv_t<<<dim3(64,32),  256, 0, stream>>>(Wv, Wqkv_t + (size_t)2048*1024, 1024, 2048, 1.f);
  conv_t<<<dim3(32,64),  256, 0, stream>>>(Wo, Wo_t, 2048, 1024, 1.f);
  conv_t<<<dim3(128,32), 256, 0, stream>>>(W1, W1_t, 1024, 4096, 1.f);
  conv_t<<<dim3(32,128), 256, 0, stream>>>(W2, W2_t, 4096, 1024, 1.f);

  ln_bf16<<<8192, 256, 0, stream>>>(x, ln1_w, ln1_b, hbuf);

  // fused QKV: [8192,4096] = hbuf @ Wqkv^T, 2048 blocks, tiles_y = 64
  gemm_nt<<<2048, 256, 0, stream>>>(hbuf, Wqkv_t, 8192, 4096, 1024, 1024, nullptr, qkv, nullptr, nullptr, 2, 64);

  for (int b = 0; b < 2; ++b){
    const s16* q_b = qkv + (size_t)b*4096*4096;
    const s16* k_b = q_b + 1024;
    const s16* v_b = q_b + 2048;
    s16* ob_b = ob + (size_t)b*4096*2048;
    ret_chunksum<<<512, 256, 0, stream>>>(k_b, v_b, US);
    ret_scan<<<128, 256, 0, stream>>>(US);
    ret_attn<<<512, 256, 0, stream>>>(q_b, k_b, v_b, US, ob_b);
  }

  // Wo: x1 = x + ob @ Wo^T   (64x128 tile, 1024 blocks, tiles_y = 128)
  gemm_nt_h<<<1024, 256, 0, stream>>>(ob, Wo_t, 8192, 1024, 2048, 2048, x1, nullptr, nullptr, x, 0, 128);
  ln_bf16<<<8192, 256, 0, stream>>>(x1, ln2_w, ln2_b, h2);

  // FFN: fb = gelu(h2 @ W1^T + b1)  [8192,4096], 2048 blocks, tiles_y = 64
  gemm_nt<<<2048, 256, 0, stream>>>(h2, W1_t, 8192, 4096, 1024, 1024, nullptr, fb, b1, nullptr, 2|1, 64);
  // out = x1 + b2 + fb @ W2^T   (64x128 tile, 1024 blocks, K=4096, tiles_y = 128)
  gemm_nt_h<<<1024, 256, 0, stream>>>(fb, W2_t, 8192, 1024, 4096, 4096, out, nullptr, b2, x1, 0, 128);
}

// Round 7
// 635.911 us; speedup vs baseline: 1.9718x; 1.0392x over previous
//
#include <hip/hip_runtime.h>
#include <math.h>

typedef short s16;
typedef __attribute__((ext_vector_type(8))) short short8;
typedef __attribute__((ext_vector_type(4))) float f32x4;

__device__ __forceinline__ float bf2f_lo(unsigned u){ return __builtin_bit_cast(float, u << 16); }
__device__ __forceinline__ float bf2f_hi(unsigned u){ return __builtin_bit_cast(float, u & 0xffff0000u); }
__device__ __forceinline__ float bf2f(unsigned short h){ return __builtin_bit_cast(float, (unsigned)h << 16); }
__device__ __forceinline__ s16 f2bf(float f){
  unsigned u = __builtin_bit_cast(unsigned, f);
  u += 0x7fffu + ((u >> 16) & 1u);
  return (s16)(u >> 16);
}
__device__ __forceinline__ void unpack8(int4 v, float* f){
  unsigned a=(unsigned)v.x, b=(unsigned)v.y, c=(unsigned)v.z, d=(unsigned)v.w;
  f[0]=bf2f_lo(a); f[1]=bf2f_hi(a); f[2]=bf2f_lo(b); f[3]=bf2f_hi(b);
  f[4]=bf2f_lo(c); f[5]=bf2f_hi(c); f[6]=bf2f_lo(d); f[7]=bf2f_hi(d);
}
// async global->LDS 16B: lds dest is wave-uniform base + lane*16
__device__ __forceinline__ void gl2lds16(const s16* g, s16* l){
  __builtin_amdgcn_global_load_lds((const __attribute__((address_space(1))) void*)g,
                                   (__attribute__((address_space(3))) void*)l, 16, 0, 0);
}

// ---------------- LayerNorm (fp32 in) -> bf16 out, D=1024, 1 block/row ------
__global__ __launch_bounds__(256) void ln_bf16(const float* __restrict__ x,
                                               const float* __restrict__ w,
                                               const float* __restrict__ b,
                                               s16* __restrict__ out){
  int row = blockIdx.x; int t = threadIdx.x;
  const float* xr = x + (size_t)row * 1024;
  float4 v = *(const float4*)(xr + t*4);
  float s = v.x + v.y + v.z + v.w;
  float ss = v.x*v.x + v.y*v.y + v.z*v.z + v.w*v.w;
  for (int o = 32; o > 0; o >>= 1){ s += __shfl_down(s, o, 64); ss += __shfl_down(ss, o, 64); }
  __shared__ float red[8];
  int wid = t >> 6, lane = t & 63;
  if (lane == 0){ red[wid] = s; red[4+wid] = ss; }
  __syncthreads();
  if (t == 0){
    float S = red[0]+red[1]+red[2]+red[3];
    float SS = red[4]+red[5]+red[6]+red[7];
    red[0] = S * (1.f/1024.f);
    red[1] = SS * (1.f/1024.f);
  }
  __syncthreads();
  float mu = red[0];
  float var = red[1] - mu*mu;
  float rstd = rsqrtf(var + 1e-6f);
  float vv[4] = {v.x, v.y, v.z, v.w};
  short4 o4;
  s16 tmp[4];
  #pragma unroll
  for (int i = 0; i < 4; ++i){
    int c = t*4 + i;
    float val = (vv[i] - mu) * rstd * w[c] + b[c];
    tmp[i] = f2bf(val);
  }
  o4.x = tmp[0]; o4.y = tmp[1]; o4.z = tmp[2]; o4.w = tmp[3];
  *(short4*)(out + (size_t)row*1024 + t*4) = o4;
}

// ---------------- transpose-convert fp32 W[K,N] -> bf16 Wt[N,K], with scale --
__global__ __launch_bounds__(256) void conv_t(const float* __restrict__ W,
                                              s16* __restrict__ Wt,
                                              int K, int N, float scale){
  __shared__ float tile[32][33];
  int n0 = blockIdx.x * 32, k0 = blockIdx.y * 32;
  int tx = threadIdx.x & 31, ty = threadIdx.x >> 5;   // ty 0..7
  #pragma unroll
  for (int i = 0; i < 4; ++i){
    int r = ty + i*8;
    tile[r][tx] = W[(size_t)(k0 + r)*N + n0 + tx];
  }
  __syncthreads();
  #pragma unroll
  for (int i = 0; i < 4; ++i){
    int r = ty + i*8;
    Wt[(size_t)(n0 + r)*K + k0 + tx] = f2bf(tile[tx][r] * scale);
  }
}

// XCD swizzle: 1D grid, tiles_y M-tiles (divisible by 8). Each XCD owns a
// disjoint M-row stripe (A fetched once, per-XCD L2); N iterated slowly so
// the B-slab stays hot across sy consecutive on-XCD blocks.
__device__ __forceinline__ void xcd_tile(int tiles_y, int& tx, int& ty){
  int id = blockIdx.x;
  int sy = tiles_y >> 3;
  int xcd = id & 7, p = id >> 3;
  ty = xcd * sy + (p % sy);
  tx = p / sy;
}

// ---------------- bf16 MFMA GEMM 128x128 tile, BK=64 dual-buffer -------------
// 1D grid = (N/128)*(M/128); tiles_y = M/128. flags: bit0 gelu, bit1 out bf16
__global__ __launch_bounds__(256,2) void gemm_nt(const s16* __restrict__ A,
                                                 const s16* __restrict__ Bt,
                                                 int M, int N, int K, int ldb,
                                                 float* __restrict__ Cf,
                                                 s16* __restrict__ Cb,
                                                 const float* __restrict__ bias,
                                                 const float* __restrict__ resid,
                                                 int flags, int tiles_y){
  __shared__ s16 As0[128*32], As1[128*32];
  __shared__ s16 Bs0[128*32], Bs1[128*32];
  int t = threadIdx.x;
  int tx, ty; xcd_tile(tiles_y, tx, ty);
  int m0 = ty * 128, n0 = tx * 128;
  int w = t >> 6, lane = t & 63;
  int wm = (w >> 1) * 64, wn = (w & 1) * 64;
  int lrow = lane & 15, lq = lane >> 4;
  f32x4 acc[4][4];
  #pragma unroll
  for (int i = 0; i < 4; ++i)
    #pragma unroll
    for (int j = 0; j < 4; ++j) acc[i][j] = (f32x4){0.f,0.f,0.f,0.f};

  const s16* Ag = A  + (size_t)(m0 + (t>>2)) * K   + (t&3)*8;
  const s16* Bg = Bt + (size_t)(n0 + (t>>2)) * ldb + (t&3)*8;
  int wo = w*512;

  for (int k0 = 0; k0 < K; k0 += 64){
    __syncthreads();
    gl2lds16(Ag + k0,                     As0 + wo);
    gl2lds16(Ag + (size_t)64*K + k0,      As0 + 2048 + wo);
    gl2lds16(Ag + k0 + 32,                As1 + wo);
    gl2lds16(Ag + (size_t)64*K + k0 + 32, As1 + 2048 + wo);
    gl2lds16(Bg + k0,                       Bs0 + wo);
    gl2lds16(Bg + (size_t)64*ldb + k0,      Bs0 + 2048 + wo);
    gl2lds16(Bg + k0 + 32,                  Bs1 + wo);
    gl2lds16(Bg + (size_t)64*ldb + k0 + 32, Bs1 + 2048 + wo);
    __syncthreads();
    short8 af[4], bfr[4];
    #pragma unroll
    for (int mi = 0; mi < 4; ++mi)
      af[mi] = *(short8*)&As0[(wm + mi*16 + lrow)*32 + lq*8];
    #pragma unroll
    for (int ni = 0; ni < 4; ++ni)
      bfr[ni] = *(short8*)&Bs0[(wn + ni*16 + lrow)*32 + lq*8];
    #pragma unroll
    for (int mi = 0; mi < 4; ++mi)
      #pragma unroll
      for (int ni = 0; ni < 4; ++ni)
        acc[mi][ni] = __builtin_amdgcn_mfma_f32_16x16x32_bf16(af[mi], bfr[ni], acc[mi][ni], 0, 0, 0);
    #pragma unroll
    for (int mi = 0; mi < 4; ++mi)
      af[mi] = *(short8*)&As1[(wm + mi*16 + lrow)*32 + lq*8];
    #pragma unroll
    for (int ni = 0; ni < 4; ++ni)
      bfr[ni] = *(short8*)&Bs1[(wn + ni*16 + lrow)*32 + lq*8];
    #pragma unroll
    for (int mi = 0; mi < 4; ++mi)
      #pragma unroll
      for (int ni = 0; ni < 4; ++ni)
        acc[mi][ni] = __builtin_amdgcn_mfma_f32_16x16x32_bf16(af[mi], bfr[ni], acc[mi][ni], 0, 0, 0);
  }

  bool do_gelu = flags & 1;
  bool out_bf = flags & 2;
  #pragma unroll
  for (int mi = 0; mi < 4; ++mi){
    #pragma unroll
    for (int ni = 0; ni < 4; ++ni){
      int gcol = n0 + wn + ni*16 + lrow;
      float bcol = bias ? bias[gcol] : 0.f;
      int grow_base = m0 + wm + mi*16 + lq*4;
      #pragma unroll
      for (int r = 0; r < 4; ++r){
        int grow = grow_base + r;
        float val = acc[mi][ni][r] + bcol;
        if (do_gelu) val = 0.5f * val * (1.f + erff(val * 0.70710678118654752f));
        if (resid) val += resid[(size_t)grow * N + gcol];
        if (out_bf) Cb[(size_t)grow * N + gcol] = f2bf(val);
        else        Cf[(size_t)grow * N + gcol] = val;
      }
    }
  }
}

// ---------------- bf16 MFMA GEMM 64x128 tile, BK=64 dual-buffer --------------
// 1D grid = (N/128)*(M/64); tiles_y = M/64. Wave w owns cols [32w,32w+32).
__global__ __launch_bounds__(256,2) void gemm_nt_h(const s16* __restrict__ A,
                                                   const s16* __restrict__ Bt,
                                                   int M, int N, int K, int ldb,
                                                   float* __restrict__ Cf,
                                                   s16* __restrict__ Cb,
                                                   const float* __restrict__ bias,
                                                   const float* __restrict__ resid,
                                                   int flags, int tiles_y){
  __shared__ s16 As0[64*32], As1[64*32];
  __shared__ s16 Bs0[128*32], Bs1[128*32];
  int t = threadIdx.x;
  int tx, ty; xcd_tile(tiles_y, tx, ty);
  int m0 = ty * 64, n0 = tx * 128;
  int w = t >> 6, lane = t & 63;
  int lrow = lane & 15, lq = lane >> 4;
  f32x4 acc[4][2];
  #pragma unroll
  for (int i = 0; i < 4; ++i)
    #pragma unroll
    for (int j = 0; j < 2; ++j) acc[i][j] = (f32x4){0.f,0.f,0.f,0.f};

  const s16* Ag = A  + (size_t)(m0 + (t>>2)) * K   + (t&3)*8;
  const s16* Bg = Bt + (size_t)(n0 + (t>>2)) * ldb + (t&3)*8;
  int wo = w*512;

  for (int k0 = 0; k0 < K; k0 += 64){
    __syncthreads();
    gl2lds16(Ag + k0,      As0 + wo);
    gl2lds16(Ag + k0 + 32, As1 + wo);
    gl2lds16(Bg + k0,                       Bs0 + wo);
    gl2lds16(Bg + (size_t)64*ldb + k0,      Bs0 + 2048 + wo);
    gl2lds16(Bg + k0 + 32,                  Bs1 + wo);
    gl2lds16(Bg + (size_t)64*ldb + k0 + 32, Bs1 + 2048 + wo);
    __syncthreads();
    short8 af[4], bfr[2];
    #pragma unroll
    for (int mi = 0; mi < 4; ++mi)
      af[mi] = *(short8*)&As0[(mi*16 + lrow)*32 + lq*8];
    #pragma unroll
    for (int ni = 0; ni < 2; ++ni)
      bfr[ni] = *(short8*)&Bs0[(w*32 + ni*16 + lrow)*32 + lq*8];
    #pragma unroll
    for (int mi = 0; mi < 4; ++mi)
      #pragma unroll
      for (int ni = 0; ni < 2; ++ni)
        acc[mi][ni] = __builtin_amdgcn_mfma_f32_16x16x32_bf16(af[mi], bfr[ni], acc[mi][ni], 0, 0, 0);
    #pragma unroll
    for (int mi = 0; mi < 4; ++mi)
      af[mi] = *(short8*)&As1[(mi*16 + lrow)*32 + lq*8];
    #pragma unroll
    for (int ni = 0; ni < 2; ++ni)
      bfr[ni] = *(short8*)&Bs1[(w*32 + ni*16 + lrow)*32 + lq*8];
    #pragma unroll
    for (int mi = 0; mi < 4; ++mi)
      #pragma unroll
      for (int ni = 0; ni < 2; ++ni)
        acc[mi][ni] = __builtin_amdgcn_mfma_f32_16x16x32_bf16(af[mi], bfr[ni], acc[mi][ni], 0, 0, 0);
  }

  bool do_gelu = flags & 1;
  bool out_bf = flags & 2;
  #pragma unroll
  for (int mi = 0; mi < 4; ++mi){
    #pragma unroll
    for (int ni = 0; ni < 2; ++ni){
      int gcol = n0 + w*32 + ni*16 + lrow;
      float bcol = bias ? bias[gcol] : 0.f;
      int grow_base = m0 + mi*16 + lq*4;
      #pragma unroll
      for (int r = 0; r < 4; ++r){
        int grow = grow_base + r;
        float val = acc[mi][ni][r] + bcol;
        if (do_gelu) val = 0.5f * val * (1.f + erff(val * 0.70710678118654752f));
        if (resid) val += resid[(size_t)grow * N + gcol];
        if (out_bf) Cb[(size_t)grow * N + gcol] = f2bf(val);
        else        Cf[(size_t)grow * N + gcol] = val;
      }
    }
  }
}

// ---------------- retention 2a (per batch): U_t[dv][dk] = (d_k*k (x) v)^T ----
// grid 512 = h(8) + n(64); k,v from fused qkv (row stride 4096)
__global__ __launch_bounds__(256,2) void ret_chunksum(const s16* __restrict__ k,
                                                      const s16* __restrict__ v,
                                                      s16* __restrict__ U){
  int bi = blockIdx.x;
  int h = bi & 7, n = bi >> 3;
  int t = threadIdx.x;
  __shared__ s16 ks[128*72];   // ks[dk][s], d_k decay folded
  __shared__ s16 vs[256*72];   // vs[dv][s]
  float log2b = log2f(1.f - exp2f(-5.f - (float)h));
  const s16* kbase = k + (size_t)(n*64)*4096 + h*128;
  const s16* vbase = v + (size_t)(n*64)*4096 + h*256;
  #pragma unroll
  for (int i = 0; i < 4; ++i){
    int e = i*2048 + t*8;
    int s = e >> 7, dk = e & 127;
    int4 kv = *(const int4*)(kbase + (size_t)s*4096 + dk);
    float f[8]; unpack8(kv, f);
    float dec = exp2f(log2b * (float)(63 - s));
    #pragma unroll
    for (int j = 0; j < 8; ++j) ks[(dk+j)*72 + s] = f2bf(f[j]*dec);
  }
  #pragma unroll
  for (int i = 0; i < 8; ++i){
    int e = i*2048 + t*8;
    int s = e >> 8, dv = e & 255;
    int4 vv = *(const int4*)(vbase + (size_t)s*4096 + dv);
    s16 tmp[8]; *(int4*)tmp = vv;
    #pragma unroll
    for (int j = 0; j < 8; ++j) vs[(dv+j)*72 + s] = tmp[j];
  }
  __syncthreads();
  int w = t >> 6, lane = t & 63;
  int m0w = w*64;   // dv rows, 4 tiles per wave
  int lrow = lane & 15, lq = lane >> 4;
  f32x4 acc[4][8];
  #pragma unroll
  for (int mi = 0; mi < 4; ++mi)
    #pragma unroll
    for (int ni = 0; ni < 8; ++ni) acc[mi][ni] = (f32x4){0.f,0.f,0.f,0.f};
  #pragma unroll
  for (int kk = 0; kk < 64; kk += 32){
    short8 af[4], bfr[8];
    #pragma unroll
    for (int mi = 0; mi < 4; ++mi)
      af[mi] = *(short8*)&vs[(m0w + mi*16 + lrow)*72 + kk + lq*8];
    #pragma unroll
    for (int ni = 0; ni < 8; ++ni)
      bfr[ni] = *(short8*)&ks[(ni*16 + lrow)*72 + kk + lq*8];
    #pragma unroll
    for (int mi = 0; mi < 4; ++mi)
      #pragma unroll
      for (int ni = 0; ni < 8; ++ni)
        acc[mi][ni] = __builtin_amdgcn_mfma_f32_16x16x32_bf16(af[mi], bfr[ni], acc[mi][ni], 0, 0, 0);
  }
  s16* Ub = U + ((size_t)(h*64 + n))*32768;
  #pragma unroll
  for (int mi = 0; mi < 4; ++mi)
    #pragma unroll
    for (int ni = 0; ni < 8; ++ni)
      #pragma unroll
      for (int r = 0; r < 4; ++r){
        int row = m0w + mi*16 + lq*4 + r;   // dv
        int col = ni*16 + lrow;             // dk
        Ub[(size_t)row*128 + col] = f2bf(acc[mi][ni][r]);
      }
}

// ---------------- retention 2b (per batch): in-place decay prefix scan -------
__global__ __launch_bounds__(256) void ret_scan(s16* __restrict__ US){
  int tid = blockIdx.x*256 + threadIdx.x;       // 32768 threads
  int h = tid >> 12;
  int rem = tid & 4095;
  int dv = rem >> 4, dk0 = (rem & 15)*8;
  float log2b = log2f(1.f - exp2f(-5.f - (float)h));
  float dc = exp2f(log2b * 64.f);
  s16* base = US + (size_t)h*64*32768 + (size_t)dv*128 + dk0;
  float acc[8] = {0.f,0.f,0.f,0.f,0.f,0.f,0.f,0.f};
  #pragma unroll 4
  for (int n = 0; n < 64; ++n){
    s16* p = base + (size_t)n*32768;
    int4 u4 = *(const int4*)p;
    float uf[8]; unpack8(u4, uf);
    s16 sb[8];
    #pragma unroll
    for (int j = 0; j < 8; ++j) sb[j] = f2bf(acc[j]);
    *(int4*)p = *(int4*)sb;
    #pragma unroll
    for (int j = 0; j < 8; ++j) acc[j] = acc[j]*dc + uf[j];
  }
}

// ---------------- retention fused (per batch): O = mask(qk^T)@v + dq*(q@S) ---
// grid 512 = h(8) + n(64). q,k,v from fused qkv (stride 4096); S_t [h][n][256][128]
__global__ __launch_bounds__(256,2) void ret_attn(const s16* __restrict__ q,
                                                  const s16* __restrict__ k,
                                                  const s16* __restrict__ v,
                                                  const s16* __restrict__ S,
                                                  s16* __restrict__ o){
  int bi = blockIdx.x;
  int h = bi & 7, n = bi >> 3;
  int t = threadIdx.x;
  int w = t >> 6, lane = t & 63;
  int lrow = lane & 15, lq = lane >> 4;
  float log2b = log2f(1.f - exp2f(-5.f - (float)h));
  __shared__ s16 As[64*72];    // masked scores, A-operand staging
  __shared__ s16 vs[256*72];   // v^T [dv][s]

  // stage v transposed
  const s16* vbase = v + (size_t)(n*64)*4096 + h*256;
  #pragma unroll
  for (int i = 0; i < 8; ++i){
    int e = i*2048 + t*8;
    int s = e >> 8, dv = e & 255;
    int4 vv = *(const int4*)(vbase + (size_t)s*4096 + dv);
    s16 tmp[8]; *(int4*)tmp = vv;
    #pragma unroll
    for (int j = 0; j < 8; ++j) vs[(dv+j)*72 + s] = tmp[j];
  }

  // phase 1: wave w computes A[:, 16w:16w+16] = q @ k^T, masked
  const s16* qbase = q + (size_t)(n*64)*4096 + h*128;
  const s16* kbase = k + (size_t)(n*64)*4096 + h*128;
  short8 qf[4][4];   // [row-tile][kstep], reused in phase 2
  #pragma unroll
  for (int ti = 0; ti < 4; ++ti)
    #pragma unroll
    for (int c = 0; c < 4; ++c)
      qf[ti][c] = *(const short8*)(qbase + (size_t)(ti*16 + lrow)*4096 + c*32 + lq*8);
  short8 kf[4];
  #pragma unroll
  for (int c = 0; c < 4; ++c)
    kf[c] = *(const short8*)(kbase + (size_t)(16*w + lrow)*4096 + c*32 + lq*8);
  #pragma unroll
  for (int ti = 0; ti < 4; ++ti){
    f32x4 acc_a = (f32x4){0.f,0.f,0.f,0.f};
    #pragma unroll
    for (int c = 0; c < 4; ++c)
      acc_a = __builtin_amdgcn_mfma_f32_16x16x32_bf16(qf[ti][c], kf[c], acc_a, 0, 0, 0);
    #pragma unroll
    for (int r = 0; r < 4; ++r){
      int ti_idx = ti*16 + lq*4 + r;
      int s_idx = 16*w + lrow;
      int d = ti_idx - s_idx;
      float val = (d >= 0) ? acc_a[r] * exp2f(log2b * (float)d) : 0.f;
      As[ti_idx*72 + s_idx] = f2bf(val);
    }
  }
  __syncthreads();

  // phase 2: wave w owns dv cols [64w, 64w+64)
  f32x4 acc[4][4];
  #pragma unroll
  for (int mi = 0; mi < 4; ++mi)
    #pragma unroll
    for (int nj = 0; nj < 4; ++nj) acc[mi][nj] = (f32x4){0.f,0.f,0.f,0.f};

  // q @ S  (K = 128)
  const s16* Sbase = S + ((size_t)(h*64 + n)*256 + w*64)*128;
  #pragma unroll
  for (int c = 0; c < 4; ++c){
    short8 bf[4];
    #pragma unroll
    for (int nj = 0; nj < 4; ++nj)
      bf[nj] = *(const short8*)(Sbase + (size_t)(nj*16 + lrow)*128 + c*32 + lq*8);
    #pragma unroll
    for (int mi = 0; mi < 4; ++mi)
      #pragma unroll
      for (int nj = 0; nj < 4; ++nj)
        acc[mi][nj] = __builtin_amdgcn_mfma_f32_16x16x32_bf16(qf[mi][c], bf[nj], acc[mi][nj], 0, 0, 0);
  }
  // scale by d_q = b^(row+1)
  #pragma unroll
  for (int mi = 0; mi < 4; ++mi){
    #pragma unroll
    for (int r = 0; r < 4; ++r){
      float dq = exp2f(log2b * (float)(mi*16 + lq*4 + r + 1));
      #pragma unroll
      for (int nj = 0; nj < 4; ++nj) acc[mi][nj][r] *= dq;
    }
  }
  // A @ v  (K = 64)
  #pragma unroll
  for (int c = 0; c < 2; ++c){
    short8 af[4], bf[4];
    #pragma unroll
    for (int mi = 0; mi < 4; ++mi)
      af[mi] = *(short8*)&As[(mi*16 + lrow)*72 + c*32 + lq*8];
    #pragma unroll
    for (int nj = 0; nj < 4; ++nj)
      bf[nj] = *(short8*)&vs[(w*64 + nj*16 + lrow)*72 + c*32 + lq*8];
    #pragma unroll
    for (int mi = 0; mi < 4; ++mi)
      #pragma unroll
      for (int nj = 0; nj < 4; ++nj)
        acc[mi][nj] = __builtin_amdgcn_mfma_f32_16x16x32_bf16(af[mi], bf[nj], acc[mi][nj], 0, 0, 0);
  }
  // write O
  s16* obase = o + (size_t)(n*64)*2048 + h*256;
  #pragma unroll
  for (int mi = 0; mi < 4; ++mi)
    #pragma unroll
    for (int nj = 0; nj < 4; ++nj)
      #pragma unroll
      for (int r = 0; r < 4; ++r){
        int row = mi*16 + lq*4 + r;
        int col = w*64 + nj*16 + lrow;
        obase[(size_t)row*2048 + col] = f2bf(acc[mi][nj][r]);
      }
}

extern "C" void kernel_launch(void* const* d_in, const int* in_sizes, int n_in,
                              void* d_out, int out_size, void* d_ws, size_t ws_size,
                              hipStream_t stream) {
  (void)in_sizes; (void)n_in; (void)out_size; (void)ws_size;
  const float* x     = (const float*)d_in[0];
  const float* ln1_w = (const float*)d_in[1];
  const float* ln1_b = (const float*)d_in[2];
  const float* Wq    = (const float*)d_in[3];
  const float* Wk    = (const float*)d_in[4];
  const float* Wv    = (const float*)d_in[5];
  const float* Wo    = (const float*)d_in[6];
  const float* ln2_w = (const float*)d_in[7];
  const float* ln2_b = (const float*)d_in[8];
  const float* W1    = (const float*)d_in[9];
  const float* b1    = (const float*)d_in[10];
  const float* W2    = (const float*)d_in[11];
  const float* b2    = (const float*)d_in[12];
  float* out = (float*)d_out;
  char* ws = (char*)d_ws;

  // ---- static arena, peak 172 MB (lifetime-aliased) ----
  const size_t MB = 1ull << 20;
  s16* Wqkv_t = (s16*)(ws + 0*MB);   // [0,8)  rows: 0-1023 q, 1024-2047 k, 2048-4095 v
  s16* Wo_t = (s16*)(ws + 8*MB);     // [8,12)
  s16* W1_t = (s16*)(ws + 12*MB);    // [12,20)
  s16* W2_t = (s16*)(ws + 20*MB);    // [20,28)
  s16* hbuf = (s16*)(ws + 28*MB);    // [28,44)  dead after QKV gemm
  s16* h2   = (s16*)(ws + 28*MB);    // [28,44)  alias dead hbuf (post-retention)
  s16* qkv  = (s16*)(ws + 44*MB);    // [44,108) [8192,4096] bf16, dead after ret_attn(b1)
  float* x1 = (float*)(ws + 44*MB);  // [44,76)  alias dead qkv head (post-retention)
  s16* fb   = (s16*)(ws + 76*MB);    // [76,140) alias dead qkv tail + US (FFN acts)
  s16* US   = (s16*)(ws + 108*MB);   // [108,140) bf16 per-batch U->S (in-place scan)
  s16* ob   = (s16*)(ws + 140*MB);   // [140,172)

  // weight transpose-convert (DK^-0.5 folded into Wq)
  conv_t<<<dim3(32,32),  256, 0, stream>>>(Wq, Wqkv_t, 1024, 1024, 0.08838834764831845f);
  conv_t<<<dim3(32,32),  256, 0, stream>>>(Wk, Wqkv_t + (size_t)1024*1024, 1024, 1024, 1.f);
  conv_t<<<dim3(64,32),  256, 0, stream>>>(Wv, Wqkv_t + (size_t)2048*1024, 1024, 2048, 1.f);
  conv_t<<<dim3(32,64),  256, 0, stream>>>(Wo, Wo_t, 2048, 1024, 1.f);
  conv_t<<<dim3(128,32), 256, 0, stream>>>(W1, W1_t, 1024, 4096, 1.f);
  conv_t<<<dim3(32,128), 256, 0, stream>>>(W2, W2_t, 4096, 1024, 1.f);

  ln_bf16<<<8192, 256, 0, stream>>>(x, ln1_w, ln1_b, hbuf);

  // fused QKV: [8192,4096] = hbuf @ Wqkv^T, 2048 blocks, tiles_y = 64
  gemm_nt<<<2048, 256, 0, stream>>>(hbuf, Wqkv_t, 8192, 4096, 1024, 1024, nullptr, qkv, nullptr, nullptr, 2, 64);

  for (int b = 0; b < 2; ++b){
    const s16* q_b = qkv + (size_t)b*4096*4096;
    const s16* k_b = q_b + 1024;
    const s16* v_b = q_b + 2048;
    s16* ob_b = ob + (size_t)b*4096*2048;
    ret_chunksum<<<512, 256, 0, stream>>>(k_b, v_b, US);
    ret_scan<<<128, 256, 0, stream>>>(US);
    ret_attn<<<512, 256, 0, stream>>>(q_b, k_b, v_b, US, ob_b);
  }

  // Wo: x1 = x + ob @ Wo^T   (64x128 tile, 1024 blocks, tiles_y = 128)
  gemm_nt_h<<<1024, 256, 0, stream>>>(ob, Wo_t, 8192, 1024, 2048, 2048, x1, nullptr, nullptr, x, 0, 128);
  ln_bf16<<<8192, 256, 0, stream>>>(x1, ln2_w, ln2_b, h2);

  // FFN: fb = gelu(h2 @ W1^T + b1)  [8192,4096], 2048 blocks, tiles_y = 64
  gemm_nt<<<2048, 256, 0, stream>>>(h2, W1_t, 8192, 4096, 1024, 1024, nullptr, fb, b1, nullptr, 2|1, 64);
  // out = x1 + b2 + fb @ W2^T   (64x128 tile, 1024 blocks, K=4096, tiles_y = 128)
  gemm_nt_h<<<1024, 256, 0, stream>>>(fb, W2_t, 8192, 1024, 4096, 4096, out, nullptr, b2, x1, 0, 128);
}